// Round 2
// baseline (16320.126 us; speedup 1.0000x reference)
//
#include <hip/hip_runtime.h>
#include <hip/hip_bf16.h>
#include <math.h>

typedef __attribute__((ext_vector_type(8))) short short8;
typedef __attribute__((ext_vector_type(4))) float floatx4;

#define DEVFN static __device__ __forceinline__

constexpr int B = 128, T = 256, S = 64, H = 512;
constexpr int KMIX = 10, CSL = 60, OUTW = 121;
constexpr int FXW = 1088;           // padded feature row: [x(3) win(60) pad(1) h1(512) h2(512)]
constexpr int NG  = 2048;           // 4*H gate rows
constexpr int K1  = 576,  K1C = 18; // lstm1 K (padded) and 32-chunks
constexpr int K2  = 1088, K2C = 34; // lstm2

DEVFN __hip_bfloat16 bhi(float v) { return __float2bfloat16(v); }
DEVFN __hip_bfloat16 blo(float v, __hip_bfloat16 h) { return __float2bfloat16(v - __bfloat162float(h)); }

// ---------------- precompute: cast/interleave weights (hi+lo), init fx slots ----------------
// gate-interleaved row index n' = hcol*4 + gate  (gate order i,f,g,o)
__global__ __launch_bounds__(256) void k_pre(
    const float* __restrict__ x, const float* __restrict__ h1h, const float* __restrict__ h2h,
    const float* __restrict__ Wihc, const float* __restrict__ Whhc, const float* __restrict__ bc,
    const float* __restrict__ Wihl, const float* __restrict__ Whhl, const float* __restrict__ bl,
    const float* __restrict__ W2,
    __hip_bfloat16* __restrict__ fx, __hip_bfloat16* __restrict__ fxlo,
    __hip_bfloat16* __restrict__ wc1, __hip_bfloat16* __restrict__ wc1l,
    __hip_bfloat16* __restrict__ wc2, __hip_bfloat16* __restrict__ wc2l,
    __hip_bfloat16* __restrict__ w2b, float* __restrict__ bi1, float* __restrict__ bi2,
    float* __restrict__ h1fp)
{
  int idx = blockIdx.x * 256 + threadIdx.x;
  const int nwc1 = NG * K1;
  const int nwc2 = NG * K2;
  const int nw2b = 128 * 512;
  const int nbi  = 2 * NG;
  const int nfh  = B * H;
  const int nxp  = T * B * 4;
  if (idx < nwc1) {
    int n = idx / K1, col = idx - n * K1;
    int src = (n & 3) * H + (n >> 2);
    float v = (col < 63) ? Wihc[src * 63 + col]
            : (col == 63 ? 0.f : Whhc[src * 512 + (col - 64)]);
    __hip_bfloat16 h = bhi(v);
    wc1[n * K1 + col] = h;
    wc1l[n * K1 + col] = blo(v, h);
    return;
  }
  idx -= nwc1;
  if (idx < nwc2) {
    int n = idx / K2, col = idx - n * K2;
    int src = (n & 3) * H + (n >> 2);
    float v;
    if (col < 63)       v = Wihl[src * 575 + col];        // x,win part
    else if (col == 63) v = 0.f;                          // pad
    else if (col < 576) v = Wihl[src * 575 + (col - 1)];  // h1 part (orig cols 63..574)
    else                v = Whhl[src * 512 + (col - 576)];// h2 recurrent part
    __hip_bfloat16 h = bhi(v);
    wc2[n * K2 + col] = h;
    wc2l[n * K2 + col] = blo(v, h);
    return;
  }
  idx -= nwc2;
  if (idx < nw2b) {
    int n = idx >> 9, col = idx & 511;
    w2b[idx] = bhi(n < OUTW ? W2[n * 512 + col] : 0.f);
    return;
  }
  idx -= nw2b;
  if (idx < nbi) {
    int n = idx & (NG - 1);
    int src = (n & 3) * H + (n >> 2);
    if (idx < NG) bi1[n] = bc[src]; else bi2[n] = bl[src];
    return;
  }
  idx -= nbi;
  if (idx < nfh) {  // FX(-1) h1 slot (slot 0, ring 0) + fp32 copy for window
    int b = idx >> 9, j = idx & 511;
    float v = h1h[idx];
    __hip_bfloat16 h = bhi(v);
    fx[b * FXW + 64 + j] = h;
    fxlo[b * FXW + 64 + j] = blo(v, h);
    h1fp[idx] = v;
    return;
  }
  idx -= nfh;
  if (idx < nfh) {  // FX(0) h2 slot (slot 1, ring 1)
    int b = idx >> 9, j = idx & 511;
    float v = h2h[idx];
    __hip_bfloat16 h = bhi(v);
    fx[(size_t)B * FXW + b * FXW + 576 + j] = h;
    fxlo[(size_t)B * FXW + b * FXW + 576 + j] = blo(v, h);
    return;
  }
  idx -= nfh;
  if (idx < nxp) {  // x part + pad col for FX(t), t=0..T-1  (slot t+1); lo for x is dropped
    int t = idx / (B * 4); int r = idx - t * (B * 4);
    int b = r >> 2, i = r & 3;
    __hip_bfloat16 v = bhi(i < 3 ? x[(b * T + t) * 3 + i] : 0.f);
    fx[(size_t)(t + 1) * (B * FXW) + b * FXW + (i < 3 ? i : 63)] = v;
  }
}

// ---------------- attention window (fp32), 2 batch rows per block ----------------
struct WinSh {
  float hs[2 * 512];
  float pp[240];
  float ipl[60];
  float kl[20];
  float phl[128];
};

DEVFN void window_block(int bn, int tid, WinSh& w,
                        const float* __restrict__ h1fp,           // fp32 h1 (current step)
                        __hip_bfloat16* __restrict__ xwslot,      // slot to receive win at cols 3..62
                        __hip_bfloat16* __restrict__ xwlo,        // ring lo slot for same
                        const float* __restrict__ sent, const float* __restrict__ W1,
                        const float* __restrict__ b1, float* __restrict__ kprev, bool t0)
{
  int b0 = bn * 2;
  for (int i = tid; i < 2 * 512; i += 256) {
    int r = i >> 9, j = i & 511;
    w.hs[i] = h1fp[(b0 + r) * H + j];
  }
  __syncthreads();
  if (tid < 240) {  // ip partial dots: 2 rows x 30 outs x 4 k-parts
    int r = tid / 120, rem = tid - r * 120;
    int j = rem >> 2, part = rem & 3;
    const float* wp = W1 + j * 512 + part * 128;
    const float* hv = w.hs + r * 512 + part * 128;
    float s = 0.f;
    #pragma unroll 8
    for (int k = 0; k < 128; ++k) s += hv[k] * wp[k];
    w.pp[(r * 30 + j) * 4 + part] = s;
  }
  __syncthreads();
  if (tid < 60) {
    int r = tid / 30, j = tid - r * 30;
    const float* p = &w.pp[(r * 30 + j) * 4];
    w.ipl[r * 30 + j] = expf(p[0] + p[1] + p[2] + p[3] + b1[j]);
  }
  __syncthreads();
  if (tid < 20) {  // kappa recurrence: kappa_t = ip_kappa - kappa_{t-1}
    int r = tid / 10, k = tid - r * 10;
    int b = b0 + r;
    float kap = w.ipl[r * 30 + 20 + k] - (t0 ? 0.f : kprev[b * KMIX + k]);
    kprev[b * KMIX + k] = kap;
    w.kl[r * 10 + k] = kap;
  }
  __syncthreads();
  if (tid < 128) {  // phi over S=64 positions, u = s+1
    int r = tid >> 6, s0 = tid & 63;
    float u = (float)(s0 + 1);
    float acc = 0.f;
    #pragma unroll
    for (int k = 0; k < 10; ++k) {
      float d = w.kl[r * 10 + k] - u;
      acc += w.ipl[r * 30 + k] * expf(-w.ipl[r * 30 + 10 + k] * d * d);
    }
    w.phl[r * 64 + s0] = acc;
  }
  __syncthreads();
  if (tid < 120) {  // win = phi @ sentences ; store hi+lo
    int r = tid / 60, c = tid - r * 60;
    int b = b0 + r;
    float acc = 0.f;
    for (int s0 = 0; s0 < 64; ++s0) acc += w.phl[r * 64 + s0] * sent[(b * 64 + s0) * 60 + c];
    __hip_bfloat16 h = bhi(acc);
    xwslot[b * FXW + 3 + c] = h;
    xwlo[b * FXW + 3 + c] = blo(acc, h);
  }
  __syncthreads();
}

__global__ __launch_bounds__(256) void k_win0(
    __hip_bfloat16* __restrict__ fx, __hip_bfloat16* __restrict__ fxlo,
    const float* __restrict__ h1fp, const float* __restrict__ sent,
    const float* __restrict__ W1, const float* __restrict__ b1, float* __restrict__ kprev)
{
  // zero the x/pad lo columns (0,1,2,63) of all 4 ring slots — never rewritten later
  int gid = blockIdx.x * 256 + threadIdx.x;
  if (gid < 2048) {
    int slot = gid >> 9, rem = gid & 511;
    int row = rem >> 2, ci = rem & 3;
    int col = (ci < 3) ? ci : 63;
    fxlo[(size_t)slot * (B * FXW) + row * FXW + col] = bhi(0.f);
  }
  __shared__ WinSh wsh;
  window_block(blockIdx.x, threadIdx.x, wsh, h1fp,
               fx + (size_t)B * FXW /*FX(0) slot1*/, fxlo + (size_t)B * FXW /*ring1*/,
               sent, W1, b1, kprev, true);
}

// ---------------- MFMA gate GEMM, bf16x3: D = Ah·Wh + Ah·Wl + Al·Wh ----------------
// A frag: m=lane&15, k=(lane>>4)*8+j ; B frag identical on weight rows.
// C/D: col(n)=lane&15, row(m)=(lane>>4)*4+reg  [m89/m91-verified]
template <int KC>
DEVFN void lstm_tile(int bn, int tid, float* __restrict__ Gsm,
                     const __hip_bfloat16* __restrict__ A0h,   // chunks 0..1 hi (cols 0..63)
                     const __hip_bfloat16* __restrict__ A1h,   // chunks 2..   hi (cols 64..)
                     const __hip_bfloat16* __restrict__ A0l,   // chunks 0..1 lo (ring)
                     const __hip_bfloat16* __restrict__ A1l,   // chunks 2..   lo (ring)
                     const __hip_bfloat16* __restrict__ Wh,
                     const __hip_bfloat16* __restrict__ Wl)
{
  const int wv = tid >> 6, lane = tid & 63;
  const int lm = lane & 15;
  const int lk = (lane >> 4) << 3;
  const int mb = wv * 32, nb = bn * 32;
  floatx4 a00 = {0.f, 0.f, 0.f, 0.f};
  floatx4 a01 = a00, a10 = a00, a11 = a00;
  #pragma unroll
  for (int c = 0; c < KC; ++c) {
    const __hip_bfloat16* Ah = (c < 2) ? A0h : A1h;
    const __hip_bfloat16* Al = (c < 2) ? A0l : A1l;
    int col = c * 32 + lk;
    short8 va0 = *(const short8*)(Ah + (mb + lm) * FXW + col);
    short8 va1 = *(const short8*)(Ah + (mb + 16 + lm) * FXW + col);
    short8 ua0 = *(const short8*)(Al + (mb + lm) * FXW + col);
    short8 ua1 = *(const short8*)(Al + (mb + 16 + lm) * FXW + col);
    short8 vb0 = *(const short8*)(Wh + (size_t)(nb + lm) * (KC * 32) + col);
    short8 vb1 = *(const short8*)(Wh + (size_t)(nb + 16 + lm) * (KC * 32) + col);
    short8 ub0 = *(const short8*)(Wl + (size_t)(nb + lm) * (KC * 32) + col);
    short8 ub1 = *(const short8*)(Wl + (size_t)(nb + 16 + lm) * (KC * 32) + col);
    a00 = __builtin_amdgcn_mfma_f32_16x16x32_bf16(va0, vb0, a00, 0, 0, 0);
    a10 = __builtin_amdgcn_mfma_f32_16x16x32_bf16(va1, vb0, a10, 0, 0, 0);
    a01 = __builtin_amdgcn_mfma_f32_16x16x32_bf16(va0, vb1, a01, 0, 0, 0);
    a11 = __builtin_amdgcn_mfma_f32_16x16x32_bf16(va1, vb1, a11, 0, 0, 0);
    a00 = __builtin_amdgcn_mfma_f32_16x16x32_bf16(va0, ub0, a00, 0, 0, 0);
    a10 = __builtin_amdgcn_mfma_f32_16x16x32_bf16(va1, ub0, a10, 0, 0, 0);
    a01 = __builtin_amdgcn_mfma_f32_16x16x32_bf16(va0, ub1, a01, 0, 0, 0);
    a11 = __builtin_amdgcn_mfma_f32_16x16x32_bf16(va1, ub1, a11, 0, 0, 0);
    a00 = __builtin_amdgcn_mfma_f32_16x16x32_bf16(ua0, vb0, a00, 0, 0, 0);
    a10 = __builtin_amdgcn_mfma_f32_16x16x32_bf16(ua1, vb0, a10, 0, 0, 0);
    a01 = __builtin_amdgcn_mfma_f32_16x16x32_bf16(ua0, vb1, a01, 0, 0, 0);
    a11 = __builtin_amdgcn_mfma_f32_16x16x32_bf16(ua1, vb1, a11, 0, 0, 0);
  }
  int rr = (lane >> 4) << 2;
  #pragma unroll
  for (int r = 0; r < 4; ++r) {
    Gsm[(lm)      * 129 + mb      + rr + r] = a00[r];
    Gsm[(16 + lm) * 129 + mb      + rr + r] = a01[r];
    Gsm[(lm)      * 129 + mb + 16 + rr + r] = a10[r];
    Gsm[(16 + lm) * 129 + mb + 16 + rr + r] = a11[r];
  }
}

// ---------------- LSTM1 step: h1_t from [x,win]=FX(t)[0:64], h1_{t-1}=FX(t-1)[64:576] ----------------
__global__ __launch_bounds__(256) void k_lstm1(
    __hip_bfloat16* __restrict__ fx, __hip_bfloat16* __restrict__ fxlo,
    const __hip_bfloat16* __restrict__ wc1, const __hip_bfloat16* __restrict__ wc1l,
    const float* __restrict__ bi1, float* __restrict__ c1,
    const float* __restrict__ c1init, int t,
    float* __restrict__ h1fp, float* __restrict__ h1f, float* __restrict__ c1f)
{
  __shared__ float Gsm[32 * 129];
  int bn = blockIdx.x, tid = threadIdx.x;
  __hip_bfloat16* FXt  = fx + (size_t)(t + 1) * (B * FXW);
  __hip_bfloat16* FXtm = fx + (size_t)t * (B * FXW);
  __hip_bfloat16* RL1  = fxlo + (size_t)((t + 1) & 3) * (B * FXW);
  __hip_bfloat16* RL0  = fxlo + (size_t)(t & 3) * (B * FXW);
  lstm_tile<K1C>(bn, tid, Gsm, FXt, FXtm, RL1, RL0, wc1, wc1l);
  __syncthreads();
  bool t0 = (t == 0);
  #pragma unroll
  for (int i = 0; i < 4; ++i) {
    int flat = tid + i * 256;
    int m = flat >> 3, hc = flat & 7;
    int nl = hc * 4;
    float gi = Gsm[(nl + 0) * 129 + m] + bi1[bn * 32 + nl + 0];
    float gf = Gsm[(nl + 1) * 129 + m] + bi1[bn * 32 + nl + 1];
    float gg = Gsm[(nl + 2) * 129 + m] + bi1[bn * 32 + nl + 2];
    float go = Gsm[(nl + 3) * 129 + m] + bi1[bn * 32 + nl + 3];
    int hg = bn * 8 + hc;
    float cp = t0 ? c1init[m * H + hg] : c1[m * H + hg];
    float ig = 1.f / (1.f + expf(-gi));
    float fg = 1.f / (1.f + expf(-gf));
    float gt = tanhf(gg);
    float og = 1.f / (1.f + expf(-go));
    float cn = fg * cp + ig * gt;
    float hn = og * tanhf(cn);
    c1[m * H + hg] = cn;
    __hip_bfloat16 hb = bhi(hn);
    FXt[m * FXW + 64 + hg] = hb;
    RL1[m * FXW + 64 + hg] = blo(hn, hb);
    h1fp[m * H + hg] = hn;
    if (t == T - 1) { h1f[m * H + hg] = hn; c1f[m * H + hg] = cn; }
  }
}

// ---------------- LSTM2 step t (A = FX(t)[0:1088]) + fused window for step t+1 ----------------
__global__ __launch_bounds__(256) void k_lstm2(
    __hip_bfloat16* __restrict__ fx, __hip_bfloat16* __restrict__ fxlo,
    const __hip_bfloat16* __restrict__ wc2, const __hip_bfloat16* __restrict__ wc2l,
    const float* __restrict__ bi2, float* __restrict__ c2,
    const float* __restrict__ c2init, int t,
    __hip_bfloat16* __restrict__ ys2,
    const float* __restrict__ h1fp, const float* __restrict__ sent,
    const float* __restrict__ W1, const float* __restrict__ b1, float* __restrict__ kprev,
    float* __restrict__ h2f, float* __restrict__ c2f)
{
  __shared__ float Gsm[32 * 129];
  __shared__ WinSh wsh;
  int bn = blockIdx.x, tid = threadIdx.x;
  __hip_bfloat16* FXt = fx + (size_t)(t + 1) * (B * FXW);
  __hip_bfloat16* FXn = fx + (size_t)(t + 2) * (B * FXW);
  __hip_bfloat16* RL1 = fxlo + (size_t)((t + 1) & 3) * (B * FXW);
  __hip_bfloat16* RL2 = fxlo + (size_t)((t + 2) & 3) * (B * FXW);
  // window for step t+1: reads h1_t (fp32, written by k_lstm1(t)), writes FX(t+1)[3:63] hi+lo
  window_block(bn, tid, wsh, h1fp, FXn, RL2, sent, W1, b1, kprev, false);
  lstm_tile<K2C>(bn, tid, Gsm, FXt, FXt, RL1, RL1, wc2, wc2l);
  __syncthreads();
  bool t0 = (t == 0);
  #pragma unroll
  for (int i = 0; i < 4; ++i) {
    int flat = tid + i * 256;
    int m = flat >> 3, hc = flat & 7;
    int nl = hc * 4;
    float gi = Gsm[(nl + 0) * 129 + m] + bi2[bn * 32 + nl + 0];
    float gf = Gsm[(nl + 1) * 129 + m] + bi2[bn * 32 + nl + 1];
    float gg = Gsm[(nl + 2) * 129 + m] + bi2[bn * 32 + nl + 2];
    float go = Gsm[(nl + 3) * 129 + m] + bi2[bn * 32 + nl + 3];
    int hg = bn * 8 + hc;
    float cp = t0 ? c2init[m * H + hg] : c2[m * H + hg];
    float ig = 1.f / (1.f + expf(-gi));
    float fg = 1.f / (1.f + expf(-gf));
    float gt = tanhf(gg);
    float og = 1.f / (1.f + expf(-go));
    float cn = fg * cp + ig * gt;
    float hn = og * tanhf(cn);
    c2[m * H + hg] = cn;
    __hip_bfloat16 hb = bhi(hn);
    FXn[m * FXW + 576 + hg] = hb;                 // h2_t for next step
    RL2[m * FXW + 576 + hg] = blo(hn, hb);
    ys2[(size_t)(m * T + t) * H + hg] = hb;       // row (b*T+t) for final GEMM
    if (t == T - 1) { h2f[m * H + hg] = hn; c2f[m * H + hg] = cn; }
  }
}

// ---------------- final GEMM: out[BT x 121] = ys2 @ W2^T + b2 ----------------
__global__ __launch_bounds__(256) void k_out(
    const __hip_bfloat16* __restrict__ ys2, const __hip_bfloat16* __restrict__ w2b,
    const float* __restrict__ b2, float* __restrict__ dout)
{
  int bid = blockIdx.x, tid = threadIdx.x;
  int mblk = bid >> 1, nblk = bid & 1;
  int wv = tid >> 6, lane = tid & 63;
  int lm = lane & 15, lk = (lane >> 4) << 3;
  int m0 = mblk * 128 + wv * 32;
  int n0 = nblk * 64;
  floatx4 zz = {0.f, 0.f, 0.f, 0.f};
  floatx4 acc[2][4];
  #pragma unroll
  for (int mt = 0; mt < 2; ++mt)
    #pragma unroll
    for (int nt = 0; nt < 4; ++nt) acc[mt][nt] = zz;
  #pragma unroll
  for (int c = 0; c < 16; ++c) {
    int col = c * 32 + lk;
    short8 va0 = *(const short8*)(ys2 + (size_t)(m0 + lm) * 512 + col);
    short8 va1 = *(const short8*)(ys2 + (size_t)(m0 + 16 + lm) * 512 + col);
    short8 vb[4];
    #pragma unroll
    for (int nt = 0; nt < 4; ++nt)
      vb[nt] = *(const short8*)(w2b + (size_t)(n0 + nt * 16 + lm) * 512 + col);
    #pragma unroll
    for (int nt = 0; nt < 4; ++nt) {
      acc[0][nt] = __builtin_amdgcn_mfma_f32_16x16x32_bf16(va0, vb[nt], acc[0][nt], 0, 0, 0);
      acc[1][nt] = __builtin_amdgcn_mfma_f32_16x16x32_bf16(va1, vb[nt], acc[1][nt], 0, 0, 0);
    }
  }
  int rr = (lane >> 4) << 2;
  #pragma unroll
  for (int mt = 0; mt < 2; ++mt)
    #pragma unroll
    for (int nt = 0; nt < 4; ++nt)
      #pragma unroll
      for (int r = 0; r < 4; ++r) {
        int m = m0 + mt * 16 + rr + r;
        int n = n0 + nt * 16 + lm;
        if (n < OUTW) dout[(size_t)m * OUTW + n] = acc[mt][nt][r] + b2[n];
      }
}

// ---------------- host ----------------
extern "C" void kernel_launch(void* const* d_in, const int* in_sizes, int n_in,
                              void* d_out, int out_size, void* d_ws, size_t ws_size,
                              hipStream_t stream)
{
  (void)in_sizes; (void)n_in; (void)out_size; (void)ws_size;
  const float* x    = (const float*)d_in[0];
  const float* sent = (const float*)d_in[1];
  const float* h1h  = (const float*)d_in[2];
  const float* h1c  = (const float*)d_in[3];
  const float* h2h  = (const float*)d_in[4];
  const float* h2c  = (const float*)d_in[5];
  const float* Wihc = (const float*)d_in[6];
  const float* Whhc = (const float*)d_in[7];
  const float* bc   = (const float*)d_in[8];
  const float* Wihl = (const float*)d_in[9];
  const float* Whhl = (const float*)d_in[10];
  const float* bl   = (const float*)d_in[11];
  const float* W1   = (const float*)d_in[12];
  const float* b1   = (const float*)d_in[13];
  const float* W2   = (const float*)d_in[14];
  const float* b2   = (const float*)d_in[15];

  float* out = (float*)d_out;
  float* h1f = out + (size_t)B * T * OUTW;
  float* c1f = h1f + (size_t)B * H;
  float* h2f = c1f + (size_t)B * H;
  float* c2f = h2f + (size_t)B * H;

  char* p = (char*)d_ws;
  auto carve = [&](size_t bytes) { char* r = p; p += (bytes + 255) & ~(size_t)255; return r; };
  __hip_bfloat16* fx   = (__hip_bfloat16*)carve((size_t)(T + 2) * B * FXW * 2);
  __hip_bfloat16* fxlo = (__hip_bfloat16*)carve((size_t)4 * B * FXW * 2);
  __hip_bfloat16* ys2  = (__hip_bfloat16*)carve((size_t)B * T * H * 2);
  __hip_bfloat16* wc1  = (__hip_bfloat16*)carve((size_t)NG * K1 * 2);
  __hip_bfloat16* wc1l = (__hip_bfloat16*)carve((size_t)NG * K1 * 2);
  __hip_bfloat16* wc2  = (__hip_bfloat16*)carve((size_t)NG * K2 * 2);
  __hip_bfloat16* wc2l = (__hip_bfloat16*)carve((size_t)NG * K2 * 2);
  __hip_bfloat16* w2b  = (__hip_bfloat16*)carve((size_t)128 * 512 * 2);
  float* bi1  = (float*)carve((size_t)NG * 4);
  float* bi2  = (float*)carve((size_t)NG * 4);
  float* c1   = (float*)carve((size_t)B * H * 4);
  float* c2   = (float*)carve((size_t)B * H * 4);
  float* kpr  = (float*)carve((size_t)B * KMIX * 4);
  float* h1fp = (float*)carve((size_t)B * H * 4);

  k_pre<<<14608, 256, 0, stream>>>(x, h1h, h2h, Wihc, Whhc, bc, Wihl, Whhl, bl, W2,
                                   fx, fxlo, wc1, wc1l, wc2, wc2l, w2b, bi1, bi2, h1fp);
  k_win0<<<64, 256, 0, stream>>>(fx, fxlo, h1fp, sent, W1, b1, kpr);
  for (int t = 0; t < T; ++t) {
    k_lstm1<<<64, 256, 0, stream>>>(fx, fxlo, wc1, wc1l, bi1, c1, h1c, t, h1fp, h1f, c1f);
    k_lstm2<<<64, 256, 0, stream>>>(fx, fxlo, wc2, wc2l, bi2, c2, h2c, t, ys2,
                                    h1fp, sent, W1, b1, kpr, h2f, c2f);
  }
  k_out<<<512, 256, 0, stream>>>(ys2, w2b, b2, out);
}

// Round 4
// 7295.538 us; speedup vs baseline: 2.2370x; 2.2370x over previous
//
#include <hip/hip_runtime.h>
#include <hip/hip_bf16.h>
#include <math.h>

typedef __attribute__((ext_vector_type(8))) short short8;
typedef __attribute__((ext_vector_type(4))) float floatx4;

#define DEVFN static __device__ __forceinline__

constexpr int B = 128, T = 256, H = 512;
constexpr int KMIX = 10, OUTW = 121;
constexpr int FXW = 1088;           // padded feature row: [x(3) win(60) pad(1) h1(512) h2(512)]
constexpr int BFX = B * FXW;        // elements per fx time-slot
constexpr int NG  = 2048;           // 4*H gate rows
constexpr int K1  = 576,  K1C = 18; // lstm1 K (padded) and 32-chunks
constexpr int K2  = 1088, K2C = 34; // lstm2
constexpr int KW1P = 584, KW2P = 1096;  // LDS row pads (stride%128B==16B -> 2-way free)

// ---- LDS layout offsets (bytes) ----
// G1 path:
constexpr int O_WH1 = 0;                       // 32*584*2 = 37376
constexpr int O_WL1 = 37376;                   // 37376
constexpr int O_W1S = 74752;                   // 30*520*4 = 62400
constexpr int O_GSM = 137152;                  // 32*65*4 = 8320
constexpr int O_HS  = 145472;                  // 528*4 = 2112
constexpr int O_PP  = 147584;                  // 240*4
constexpr int O_IPL = 148544;                  // 30*4
constexpr int O_KL  = 148664;                  // 10*4 -> 148704
constexpr int O_PHL = 148704;                  // 64*4 -> 148960
constexpr int O_WAC = 148960;                  // 240*4 -> 149920
constexpr int O_KPR = 149920;                  // 10*4 -> 149960
constexpr int O_B1S = 149960;                  // 30*4 -> 150080
constexpr int O_BIA = 150080;                  // 32*4 -> 150208
// G2 path:
constexpr int O_WH2 = 0;                       // 32*1096*2 = 70144
constexpr int O_WL2 = 70144;                   // -> 140288
constexpr int O_GS2 = 140288;                  // 8320 -> 148608
constexpr int O_BI2 = 148608;                  // 128 -> 148736
constexpr int LDS_SZ = 150272;

DEVFN __hip_bfloat16 bhi(float v) { return __float2bfloat16(v); }
DEVFN __hip_bfloat16 blo(float v, __hip_bfloat16 h) { return __float2bfloat16(v - __bfloat162float(h)); }

DEVFN void fence_rel() { __builtin_amdgcn_fence(__ATOMIC_RELEASE, "agent"); }
DEVFN void fence_acq() { __builtin_amdgcn_fence(__ATOMIC_ACQUIRE, "agent"); }

DEVFN void gbar(int* ctr, int target) {
  __syncthreads();
  if (threadIdx.x == 0) {
    fence_rel();
    __hip_atomic_fetch_add(ctr, 1, __ATOMIC_RELAXED, __HIP_MEMORY_SCOPE_AGENT);
    long g = 0;
    while (__hip_atomic_load(ctr, __ATOMIC_RELAXED, __HIP_MEMORY_SCOPE_AGENT) < target &&
           g < (1L << 24)) { ++g; __builtin_amdgcn_s_sleep(2); }
    fence_acq();
  }
  __syncthreads();
}
DEVFN void waitge(int* flag, int target) {
  __syncthreads();
  if (threadIdx.x == 0) {
    long g = 0;
    while (__hip_atomic_load(flag, __ATOMIC_RELAXED, __HIP_MEMORY_SCOPE_AGENT) < target &&
           g < (1L << 24)) { ++g; __builtin_amdgcn_s_sleep(2); }
    fence_acq();
  }
  __syncthreads();
}

// ---------------- precompute: cast/interleave weights (hi+lo), init fx slots ----------------
// gate-interleaved row index n' = hcol*4 + gate  (gate order i,f,g,o)
__global__ __launch_bounds__(256) void k_pre(
    const float* __restrict__ x, const float* __restrict__ h1h, const float* __restrict__ h2h,
    const float* __restrict__ Wihc, const float* __restrict__ Whhc, const float* __restrict__ bc,
    const float* __restrict__ Wihl, const float* __restrict__ Whhl, const float* __restrict__ bl,
    const float* __restrict__ W2,
    __hip_bfloat16* __restrict__ fx, __hip_bfloat16* __restrict__ fxlo,
    __hip_bfloat16* __restrict__ wc1, __hip_bfloat16* __restrict__ wc1l,
    __hip_bfloat16* __restrict__ wc2, __hip_bfloat16* __restrict__ wc2l,
    __hip_bfloat16* __restrict__ w2b, float* __restrict__ bi1, float* __restrict__ bi2,
    float* __restrict__ h1fp, int* __restrict__ ctl)
{
  int idx = blockIdx.x * 256 + threadIdx.x;
  const int nwc1 = NG * K1;
  const int nwc2 = NG * K2;
  const int nw2b = 128 * 512;
  const int nbi  = 2 * NG;
  const int nfh  = B * H;
  const int nxp  = T * B * 4;
  const int nxlo = 8 * B * 4;
  const int nctl = 512;
  if (idx < nwc1) {
    int n = idx / K1, col = idx - n * K1;
    int src = (n & 3) * H + (n >> 2);
    float v = (col < 63) ? Wihc[src * 63 + col]
            : (col == 63 ? 0.f : Whhc[src * 512 + (col - 64)]);
    __hip_bfloat16 h = bhi(v);
    wc1[n * K1 + col] = h;
    wc1l[n * K1 + col] = blo(v, h);
    return;
  }
  idx -= nwc1;
  if (idx < nwc2) {
    int n = idx / K2, col = idx - n * K2;
    int src = (n & 3) * H + (n >> 2);
    float v;
    if (col < 63)       v = Wihl[src * 575 + col];
    else if (col == 63) v = 0.f;
    else if (col < 576) v = Wihl[src * 575 + (col - 1)];
    else                v = Whhl[src * 512 + (col - 576)];
    __hip_bfloat16 h = bhi(v);
    wc2[n * K2 + col] = h;
    wc2l[n * K2 + col] = blo(v, h);
    return;
  }
  idx -= nwc2;
  if (idx < nw2b) {
    int n = idx >> 9, col = idx & 511;
    w2b[idx] = bhi(n < OUTW ? W2[n * 512 + col] : 0.f);
    return;
  }
  idx -= nw2b;
  if (idx < nbi) {
    int n = idx & (NG - 1);
    int src = (n & 3) * H + (n >> 2);
    if (idx < NG) bi1[n] = bc[src]; else bi2[n] = bl[src];
    return;
  }
  idx -= nbi;
  if (idx < nfh) {  // FX(-1)=slot0 h1 + fp32 copy
    int b = idx >> 9, j = idx & 511;
    float v = h1h[idx];
    __hip_bfloat16 h = bhi(v);
    fx[b * FXW + 64 + j] = h;
    fxlo[b * FXW + 64 + j] = blo(v, h);
    h1fp[idx] = v;
    return;
  }
  idx -= nfh;
  if (idx < nfh) {  // FX(0)=slot1 h2
    int b = idx >> 9, j = idx & 511;
    float v = h2h[idx];
    __hip_bfloat16 h = bhi(v);
    fx[(size_t)BFX + b * FXW + 576 + j] = h;
    fxlo[(size_t)BFX + b * FXW + 576 + j] = blo(v, h);
    return;
  }
  idx -= nfh;
  if (idx < nxp) {  // x + pad col for FX(t) -> slot t+1
    int t = idx / (B * 4); int r = idx - t * (B * 4);
    int b = r >> 2, i = r & 3;
    __hip_bfloat16 v = bhi(i < 3 ? x[(b * T + t) * 3 + i] : 0.f);
    fx[(size_t)(t + 1) * BFX + b * FXW + (i < 3 ? i : 63)] = v;
    return;
  }
  idx -= nxp;
  if (idx < nxlo) {  // zero x/pad lo cols of all 8 ring slots
    int slot = idx >> 9, rem = idx & 511;
    int row = rem >> 2, ci = rem & 3;
    int col = (ci < 3) ? ci : 63;
    fxlo[(size_t)slot * BFX + row * FXW + col] = bhi(0.f);
    return;
  }
  idx -= nxlo;
  if (idx < nctl) ctl[idx] = 0;
}

// ---------------- bf16x3 MFMA over chunk range [cbeg,cend); B from LDS ----------------
template <int KWP>
DEVFN void gemm_range(int tid, const __hip_bfloat16* __restrict__ Ah_base,
                      const __hip_bfloat16* __restrict__ Al_base, int m0,
                      const __hip_bfloat16* __restrict__ Wh, const __hip_bfloat16* __restrict__ Wl,
                      int cbeg, int cend, floatx4& acc0, floatx4& acc1)
{
  const int lane = tid & 63, wv = tid >> 6;
  const int lm = lane & 15, lk = (lane >> 4) << 3;
  const __hip_bfloat16* Arh = Ah_base + (size_t)(m0 + wv * 16 + lm) * FXW;
  const __hip_bfloat16* Arl = Al_base + (size_t)(m0 + wv * 16 + lm) * FXW;
  const __hip_bfloat16* W0h = Wh + lm * KWP;
  const __hip_bfloat16* W1h = Wh + (16 + lm) * KWP;
  const __hip_bfloat16* W0l = Wl + lm * KWP;
  const __hip_bfloat16* W1l = Wl + (16 + lm) * KWP;
  #pragma unroll 4
  for (int c = cbeg; c < cend; ++c) {
    int col = c * 32 + lk;
    short8 va  = *(const short8*)(Arh + col);
    short8 ua  = *(const short8*)(Arl + col);
    short8 vb0 = *(const short8*)(W0h + col);
    short8 vb1 = *(const short8*)(W1h + col);
    short8 ub0 = *(const short8*)(W0l + col);
    short8 ub1 = *(const short8*)(W1l + col);
    acc0 = __builtin_amdgcn_mfma_f32_16x16x32_bf16(va, vb0, acc0, 0, 0, 0);
    acc1 = __builtin_amdgcn_mfma_f32_16x16x32_bf16(va, vb1, acc1, 0, 0, 0);
    acc0 = __builtin_amdgcn_mfma_f32_16x16x32_bf16(va, ub0, acc0, 0, 0, 0);
    acc1 = __builtin_amdgcn_mfma_f32_16x16x32_bf16(va, ub1, acc1, 0, 0, 0);
    acc0 = __builtin_amdgcn_mfma_f32_16x16x32_bf16(ua, vb0, acc0, 0, 0, 0);
    acc1 = __builtin_amdgcn_mfma_f32_16x16x32_bf16(ua, vb1, acc1, 0, 0, 0);
  }
}

DEVFN void store_gsm(int tid, float* Gsm, floatx4 a0, floatx4 a1) {
  const int lane = tid & 63, wv = tid >> 6;
  const int lm = lane & 15, rr = (lane >> 4) << 2;
  #pragma unroll
  for (int r = 0; r < 4; ++r) {
    Gsm[lm * 65 + wv * 16 + rr + r]        = a0[r];
    Gsm[(16 + lm) * 65 + wv * 16 + rr + r] = a1[r];
  }
}

// ---------------- persistent fused kernel ----------------
__global__ __launch_bounds__(256, 1) void k_persist(
    __hip_bfloat16* __restrict__ fx, __hip_bfloat16* __restrict__ fxlo,
    const __hip_bfloat16* __restrict__ wc1, const __hip_bfloat16* __restrict__ wc1l,
    const __hip_bfloat16* __restrict__ wc2, const __hip_bfloat16* __restrict__ wc2l,
    const float* __restrict__ bi1, const float* __restrict__ bi2,
    const float* __restrict__ c1init, const float* __restrict__ c2init,
    float* __restrict__ h1fp, __hip_bfloat16* __restrict__ ys2,
    const float* __restrict__ sent, const float* __restrict__ W1, const float* __restrict__ b1,
    int* __restrict__ ctl,
    float* __restrict__ h1f, float* __restrict__ c1f,
    float* __restrict__ h2f, float* __restrict__ c2f)
{
  extern __shared__ char sm[];
  const int gid = blockIdx.x, tid = threadIdx.x;

  int* ctrA   = ctl;          // [mh] stride 32 ints
  int* ctrB   = ctl + 64;
  int* ctr2   = ctl + 128;
  int* g1done = ctl + 192;
  int* g2done = ctl + 256;

  if (gid < 128) {
    // ================= G1: lstm1 + window chain =================
    const int nt1 = gid >> 1, mh = gid & 1;
    const int n0 = nt1 * 32, m0 = mh * 64;
    const int brow = mh * 64 + nt1;          // window row owned by this block
    __hip_bfloat16* smWh = (__hip_bfloat16*)(sm + O_WH1);
    __hip_bfloat16* smWl = (__hip_bfloat16*)(sm + O_WL1);
    float* smW1  = (float*)(sm + O_W1S);
    float* Gsm   = (float*)(sm + O_GSM);
    float* hs    = (float*)(sm + O_HS);
    float* pp    = (float*)(sm + O_PP);
    float* ipl   = (float*)(sm + O_IPL);
    float* kl    = (float*)(sm + O_KL);
    float* phl   = (float*)(sm + O_PHL);
    float* wac   = (float*)(sm + O_WAC);
    float* kpr   = (float*)(sm + O_KPR);
    float* b1s   = (float*)(sm + O_B1S);
    float* bia   = (float*)(sm + O_BIA);

    // stage weights (hi+lo), W1, b1, bias
    for (int i = tid; i < 32 * 72; i += 256) {
      int r = i / 72, c8 = (i - r * 72) * 8;
      *(short8*)(smWh + r * KW1P + c8) = *(const short8*)(wc1  + (size_t)(n0 + r) * K1 + c8);
      *(short8*)(smWl + r * KW1P + c8) = *(const short8*)(wc1l + (size_t)(n0 + r) * K1 + c8);
    }
    for (int i = tid; i < 30 * 512; i += 256) {
      int j = i >> 9, c = i & 511;
      smW1[j * 520 + (c >> 6) * 65 + (c & 63)] = W1[i];
    }
    if (tid < 30) b1s[tid] = b1[tid];
    if (tid < 10) kpr[tid] = 0.f;
    if (tid < 32) bia[tid] = bi1[n0 + tid];
    __syncthreads();

    // c-state in registers
    float creg[2];
    #pragma unroll
    for (int i = 0; i < 2; ++i) {
      int flat = tid + i * 256;
      creg[i] = c1init[(m0 + (flat >> 3)) * H + nt1 * 8 + (flat & 7)];
    }

    for (int t = 0; t < T; ++t) {
      __hip_bfloat16* FX1 = fx + (size_t)(t + 1) * BFX;
      __hip_bfloat16* FX0 = fx + (size_t)t * BFX;
      __hip_bfloat16* RL1 = fxlo + (size_t)((t + 1) & 7) * BFX;
      __hip_bfloat16* RL0 = fxlo + (size_t)(t & 7) * BFX;

      if (t >= 8) waitge(&g2done[mh * 32], t - 7);   // ring backpressure

      // ---- window(t) for row brow: reads h1fp (=h1_{t-1}) ----
      for (int i = tid; i < 512; i += 256)
        hs[(i >> 6) * 66 + (i & 63)] = h1fp[brow * H + i];
      __syncthreads();
      if (tid < 240) {
        int j = tid >> 3, p = tid & 7;
        const float* wp = smW1 + j * 520 + p * 65;
        const float* hv = hs + p * 66;
        float s = 0.f;
        #pragma unroll 8
        for (int k = 0; k < 64; ++k) s += hv[k] * wp[k];
        pp[tid] = s;
      }
      __syncthreads();
      if (tid < 30) {
        float s = b1s[tid];
        #pragma unroll
        for (int p = 0; p < 8; ++p) s += pp[tid * 8 + p];
        ipl[tid] = expf(s);
      }
      __syncthreads();
      if (tid < 10) {
        float kap = ipl[20 + tid] - kpr[tid];
        kpr[tid] = kap;
        kl[tid] = kap;
      }
      __syncthreads();
      if (tid < 64) {
        float u = (float)(tid + 1);
        float acc = 0.f;
        #pragma unroll
        for (int k = 0; k < 10; ++k) {
          float d = kl[k] - u;
          acc += ipl[k] * expf(-ipl[10 + k] * d * d);
        }
        phl[tid] = acc;
      }
      __syncthreads();
      if (tid < 240) {
        int c = tid >> 2, p = tid & 3;
        float acc = 0.f;
        #pragma unroll
        for (int s0 = 0; s0 < 16; ++s0)
          acc += phl[p * 16 + s0] * sent[(brow * 64 + p * 16 + s0) * 60 + c];
        wac[tid] = acc;
      }
      __syncthreads();
      if (tid < 60) {
        float v = wac[tid * 4] + wac[tid * 4 + 1] + wac[tid * 4 + 2] + wac[tid * 4 + 3];
        __hip_bfloat16 h = bhi(v);
        FX1[brow * FXW + 3 + tid] = h;
        RL1[brow * FXW + 3 + tid] = blo(v, h);
      }

      gbar(&ctrA[mh * 32], 64 * (t + 1));   // win_t published within mh-half

      // ---- gate GEMM ----
      floatx4 a0 = {0.f, 0.f, 0.f, 0.f}, a1 = a0;
      gemm_range<KW1P>(tid, FX1, RL1, m0, smWh, smWl, 0, 2, a0, a1);    // x,win
      gemm_range<KW1P>(tid, FX0, RL0, m0, smWh, smWl, 2, K1C, a0, a1);  // h1_{t-1}
      store_gsm(tid, Gsm, a0, a1);
      __syncthreads();

      // ---- epilogue ----
      #pragma unroll
      for (int i = 0; i < 2; ++i) {
        int flat = tid + i * 256;
        int ml = flat >> 3, hc = flat & 7, cl = hc * 4;
        float gi = Gsm[(cl + 0) * 65 + ml] + bia[cl + 0];
        float gf = Gsm[(cl + 1) * 65 + ml] + bia[cl + 1];
        float gg = Gsm[(cl + 2) * 65 + ml] + bia[cl + 2];
        float go = Gsm[(cl + 3) * 65 + ml] + bia[cl + 3];
        float ig = 1.f / (1.f + expf(-gi));
        float fg = 1.f / (1.f + expf(-gf));
        float gt = tanhf(gg);
        float og = 1.f / (1.f + expf(-go));
        float cn = fg * creg[i] + ig * gt;
        float hn = og * tanhf(cn);
        creg[i] = cn;
        int m = m0 + ml, hg = nt1 * 8 + hc;
        __hip_bfloat16 hb = bhi(hn);
        FX1[m * FXW + 64 + hg] = hb;
        RL1[m * FXW + 64 + hg] = blo(hn, hb);
        h1fp[m * H + hg] = hn;
        if (t == T - 1) { h1f[m * H + hg] = hn; c1f[m * H + hg] = cn; }
      }

      gbar(&ctrB[mh * 32], 64 * (t + 1));   // h1_t published
      if (nt1 == 0 && tid == 0)
        __hip_atomic_store(&g1done[mh * 32], t + 1, __ATOMIC_RELEASE, __HIP_MEMORY_SCOPE_AGENT);
    }
  } else {
    // ================= G2: lstm2 chain =================
    const int g = gid - 128;
    const int nt2 = g >> 1, mh = g & 1;
    const int n0 = nt2 * 32, m0 = mh * 64;
    __hip_bfloat16* smWh = (__hip_bfloat16*)(sm + O_WH2);
    __hip_bfloat16* smWl = (__hip_bfloat16*)(sm + O_WL2);
    float* Gsm = (float*)(sm + O_GS2);
    float* bia = (float*)(sm + O_BI2);

    for (int i = tid; i < 32 * 136; i += 256) {
      int r = i / 136, c8 = (i - r * 136) * 8;
      *(short8*)(smWh + r * KW2P + c8) = *(const short8*)(wc2  + (size_t)(n0 + r) * K2 + c8);
      *(short8*)(smWl + r * KW2P + c8) = *(const short8*)(wc2l + (size_t)(n0 + r) * K2 + c8);
    }
    if (tid < 32) bia[tid] = bi2[n0 + tid];
    __syncthreads();

    float creg[2];
    #pragma unroll
    for (int i = 0; i < 2; ++i) {
      int flat = tid + i * 256;
      creg[i] = c2init[(m0 + (flat >> 3)) * H + nt2 * 8 + (flat & 7)];
    }

    for (int t = 0; t < T; ++t) {
      __hip_bfloat16* FX1 = fx + (size_t)(t + 1) * BFX;
      __hip_bfloat16* FX2 = fx + (size_t)(t + 2) * BFX;
      __hip_bfloat16* RL1 = fxlo + (size_t)((t + 1) & 7) * BFX;
      __hip_bfloat16* RL2 = fxlo + (size_t)((t + 2) & 7) * BFX;

      floatx4 a0 = {0.f, 0.f, 0.f, 0.f}, a1 = a0;
      // h2-part first: depends only on own-group step t-1
      gemm_range<KW2P>(tid, FX1, RL1, m0, smWh, smWl, K1C, K2C, a0, a1);
      // wait for lstm1 half to publish win_t, h1_t
      waitge(&g1done[mh * 32], t + 1);
      gemm_range<KW2P>(tid, FX1, RL1, m0, smWh, smWl, 0, K1C, a0, a1);
      store_gsm(tid, Gsm, a0, a1);
      __syncthreads();

      #pragma unroll
      for (int i = 0; i < 2; ++i) {
        int flat = tid + i * 256;
        int ml = flat >> 3, hc = flat & 7, cl = hc * 4;
        float gi = Gsm[(cl + 0) * 65 + ml] + bia[cl + 0];
        float gf = Gsm[(cl + 1) * 65 + ml] + bia[cl + 1];
        float gg = Gsm[(cl + 2) * 65 + ml] + bia[cl + 2];
        float go = Gsm[(cl + 3) * 65 + ml] + bia[cl + 3];
        float ig = 1.f / (1.f + expf(-gi));
        float fg = 1.f / (1.f + expf(-gf));
        float gt = tanhf(gg);
        float og = 1.f / (1.f + expf(-go));
        float cn = fg * creg[i] + ig * gt;
        float hn = og * tanhf(cn);
        creg[i] = cn;
        int m = m0 + ml, hg = nt2 * 8 + hc;
        __hip_bfloat16 hb = bhi(hn);
        FX2[m * FXW + 576 + hg] = hb;
        RL2[m * FXW + 576 + hg] = blo(hn, hb);
        ys2[(size_t)(m * T + t) * H + hg] = hb;
        if (t == T - 1) { h2f[m * H + hg] = hn; c2f[m * H + hg] = cn; }
      }

      gbar(&ctr2[mh * 32], 64 * (t + 1));   // h2_t published within mh-half
      if (nt2 == 0 && tid == 0)
        __hip_atomic_store(&g2done[mh * 32], t + 1, __ATOMIC_RELEASE, __HIP_MEMORY_SCOPE_AGENT);
    }
  }
}

// ---------------- final GEMM: out[BT x 121] = ys2 @ W2^T + b2 ----------------
__global__ __launch_bounds__(256) void k_out(
    const __hip_bfloat16* __restrict__ ys2, const __hip_bfloat16* __restrict__ w2b,
    const float* __restrict__ b2, float* __restrict__ dout)
{
  int bid = blockIdx.x, tid = threadIdx.x;
  int mblk = bid >> 1, nblk = bid & 1;
  int wv = tid >> 6, lane = tid & 63;
  int lm = lane & 15, lk = (lane >> 4) << 3;
  int m0 = mblk * 128 + wv * 32;
  int n0 = nblk * 64;
  floatx4 zz = {0.f, 0.f, 0.f, 0.f};
  floatx4 acc[2][4];
  #pragma unroll
  for (int mt = 0; mt < 2; ++mt)
    #pragma unroll
    for (int nt = 0; nt < 4; ++nt) acc[mt][nt] = zz;
  #pragma unroll
  for (int c = 0; c < 16; ++c) {
    int col = c * 32 + lk;
    short8 va0 = *(const short8*)(ys2 + (size_t)(m0 + lm) * 512 + col);
    short8 va1 = *(const short8*)(ys2 + (size_t)(m0 + 16 + lm) * 512 + col);
    short8 vb[4];
    #pragma unroll
    for (int nt = 0; nt < 4; ++nt)
      vb[nt] = *(const short8*)(w2b + (size_t)(n0 + nt * 16 + lm) * 512 + col);
    #pragma unroll
    for (int nt = 0; nt < 4; ++nt) {
      acc[0][nt] = __builtin_amdgcn_mfma_f32_16x16x32_bf16(va0, vb[nt], acc[0][nt], 0, 0, 0);
      acc[1][nt] = __builtin_amdgcn_mfma_f32_16x16x32_bf16(va1, vb[nt], acc[1][nt], 0, 0, 0);
    }
  }
  int rr = (lane >> 4) << 2;
  #pragma unroll
  for (int mt = 0; mt < 2; ++mt)
    #pragma unroll
    for (int nt = 0; nt < 4; ++nt)
      #pragma unroll
      for (int r = 0; r < 4; ++r) {
        int m = m0 + mt * 16 + rr + r;
        int n = n0 + nt * 16 + lm;
        if (n < OUTW) dout[(size_t)m * OUTW + n] = acc[mt][nt][r] + b2[n];
      }
}

// ---------------- host ----------------
extern "C" void kernel_launch(void* const* d_in, const int* in_sizes, int n_in,
                              void* d_out, int out_size, void* d_ws, size_t ws_size,
                              hipStream_t stream)
{
  (void)in_sizes; (void)n_in; (void)out_size; (void)ws_size;
  const float* x    = (const float*)d_in[0];
  const float* sent = (const float*)d_in[1];
  const float* h1h  = (const float*)d_in[2];
  const float* h1c  = (const float*)d_in[3];
  const float* h2h  = (const float*)d_in[4];
  const float* h2c  = (const float*)d_in[5];
  const float* Wihc = (const float*)d_in[6];
  const float* Whhc = (const float*)d_in[7];
  const float* bc   = (const float*)d_in[8];
  const float* Wihl = (const float*)d_in[9];
  const float* Whhl = (const float*)d_in[10];
  const float* bl   = (const float*)d_in[11];
  const float* W1   = (const float*)d_in[12];
  const float* b1   = (const float*)d_in[13];
  const float* W2   = (const float*)d_in[14];
  const float* b2   = (const float*)d_in[15];

  float* out = (float*)d_out;
  float* h1f = out + (size_t)B * T * OUTW;
  float* c1f = h1f + (size_t)B * H;
  float* h2f = c1f + (size_t)B * H;
  float* c2f = h2f + (size_t)B * H;

  char* p = (char*)d_ws;
  auto carve = [&](size_t bytes) { char* r = p; p += (bytes + 255) & ~(size_t)255; return r; };
  __hip_bfloat16* fx   = (__hip_bfloat16*)carve((size_t)(T + 2) * BFX * 2);
  __hip_bfloat16* fxlo = (__hip_bfloat16*)carve((size_t)8 * BFX * 2);
  __hip_bfloat16* ys2  = (__hip_bfloat16*)carve((size_t)B * T * H * 2);
  __hip_bfloat16* wc1  = (__hip_bfloat16*)carve((size_t)NG * K1 * 2);
  __hip_bfloat16* wc1l = (__hip_bfloat16*)carve((size_t)NG * K1 * 2);
  __hip_bfloat16* wc2  = (__hip_bfloat16*)carve((size_t)NG * K2 * 2);
  __hip_bfloat16* wc2l = (__hip_bfloat16*)carve((size_t)NG * K2 * 2);
  __hip_bfloat16* w2b  = (__hip_bfloat16*)carve((size_t)128 * 512 * 2);
  float* bi1  = (float*)carve((size_t)NG * 4);
  float* bi2  = (float*)carve((size_t)NG * 4);
  float* h1fp = (float*)carve((size_t)B * H * 4);
  int*   ctl  = (int*)carve((size_t)512 * 4);

  static bool attr_set = false;
  if (!attr_set) {
    (void)hipFuncSetAttribute((const void*)k_persist,
                              hipFuncAttributeMaxDynamicSharedMemorySize, LDS_SZ);
    attr_set = true;
  }

  k_pre<<<14626, 256, 0, stream>>>(x, h1h, h2h, Wihc, Whhc, bc, Wihl, Whhl, bl, W2,
                                   fx, fxlo, wc1, wc1l, wc2, wc2l, w2b, bi1, bi2, h1fp, ctl);
  k_persist<<<256, 256, LDS_SZ, stream>>>(fx, fxlo, wc1, wc1l, wc2, wc2l, bi1, bi2,
                                          h1c, h2c, h1fp, ys2, sent, W1, b1, ctl,
                                          h1f, c1f, h2f, c2f);
  k_out<<<512, 256, 0, stream>>>(ys2, w2b, b2, out);
}

// Round 5
// 3522.312 us; speedup vs baseline: 4.6334x; 2.0712x over previous
//
#include <hip/hip_runtime.h>
#include <hip/hip_bf16.h>
#include <math.h>

typedef __attribute__((ext_vector_type(8))) short short8;
typedef __attribute__((ext_vector_type(4))) float floatx4;

#define DEVFN static __device__ __forceinline__

constexpr int B = 128, T = 256, H = 512;
constexpr int OUTW = 121;
// fxHL slot row layout (per batch row, per time slot), elems:
//   hi: [x(3) win(60) pad(1) h1(512) h2(512)] = 1088
//   lo: cols 0..575 only (x,win,h1)           = 576
constexpr int SLOTW = 1664;              // row stride in elems (hi 1088 + lo 576)
constexpr int LOOF  = 1088;              // lo region offset within row
constexpr int SLOTE = B * SLOTW;         // elems per time slot
constexpr int NSLOT = T + 2;
constexpr int NG  = 2048;                // 4*H gate rows (interleaved n' = hcol*4+gate)
constexpr int K1  = 576,  K1C = 18;
constexpr int K2  = 1088, K2C = 34;
constexpr int KW1P = 584, KW2P = 1096;   // LDS weight row pads

// ---- LDS offsets (bytes) ----
constexpr int O_WH1 = 0;                 // 32*584*2
constexpr int O_WL1 = 37376;
constexpr int O_W1S = 74752;             // 30*520*4
constexpr int O_GSM = 137152;            // 32*65*4
constexpr int O_HS  = 145472;            // 528*4 (reused as winv[60] later)
constexpr int O_PP  = 147584;            // 240*4
constexpr int O_IPL = 148544;            // 30*4
constexpr int O_KL  = 148664;
constexpr int O_PHL = 148704;            // 64*4
constexpr int O_WAC = 148960;            // 240*4
constexpr int O_KPR = 149920;
constexpr int O_B1S = 149960;
constexpr int O_BIA = 150080;            // 32*4
constexpr int O_WH2 = 0;                 // 32*1096*2
constexpr int O_WL2 = 70144;
constexpr int O_GS2 = 140288;
constexpr int O_BI2 = 148608;
constexpr int LDS_SZ = 150272;

DEVFN __hip_bfloat16 bhi(float v) { return __float2bfloat16(v); }
DEVFN __hip_bfloat16 blo(float v, __hip_bfloat16 h) { return __float2bfloat16(v - __bfloat162float(h)); }
DEVFN float bf2f(__hip_bfloat16 h) { return __bfloat162float(h); }
DEVFN unsigned short bbits(__hip_bfloat16 h) { union { __hip_bfloat16 h; unsigned short u; } c; c.h = h; return c.u; }
DEVFN unsigned int pack2(float a, float b) {
  return (unsigned int)bbits(bhi(a)) | ((unsigned int)bbits(bhi(b)) << 16);
}
DEVFN void ast(unsigned int* p, unsigned int v) {
  __hip_atomic_store(p, v, __ATOMIC_RELAXED, __HIP_MEMORY_SCOPE_AGENT);
}

// fence-free barrier: drain own stores (write-through atomics) then count.
DEVFN void gbar(int* ctr, int target) {
  asm volatile("s_waitcnt vmcnt(0)" ::: "memory");
  __syncthreads();
  if (threadIdx.x == 0) {
    __hip_atomic_fetch_add(ctr, 1, __ATOMIC_RELAXED, __HIP_MEMORY_SCOPE_AGENT);
    int g = 0;
    while (__hip_atomic_load(ctr, __ATOMIC_RELAXED, __HIP_MEMORY_SCOPE_AGENT) < target &&
           g < (1 << 22)) { ++g; __builtin_amdgcn_s_sleep(1); }
  }
  __syncthreads();
}
DEVFN void waitge(int* ctr, int target) {
  __syncthreads();
  if (threadIdx.x == 0) {
    int g = 0;
    while (__hip_atomic_load(ctr, __ATOMIC_RELAXED, __HIP_MEMORY_SCOPE_AGENT) < target &&
           g < (1 << 22)) { ++g; __builtin_amdgcn_s_sleep(1); }
  }
  __syncthreads();
}

// ---------------- precompute ----------------
__global__ __launch_bounds__(256) void k_pre(
    const float* __restrict__ x, const float* __restrict__ h1h, const float* __restrict__ h2h,
    const float* __restrict__ Wihc, const float* __restrict__ Whhc, const float* __restrict__ bc,
    const float* __restrict__ Wihl, const float* __restrict__ Whhl, const float* __restrict__ bl,
    const float* __restrict__ W2,
    __hip_bfloat16* __restrict__ fxHL,
    __hip_bfloat16* __restrict__ wc1, __hip_bfloat16* __restrict__ wc1l,
    __hip_bfloat16* __restrict__ wc2, __hip_bfloat16* __restrict__ wc2l,
    __hip_bfloat16* __restrict__ w2b, float* __restrict__ bi1, float* __restrict__ bi2,
    int* __restrict__ ctl)
{
  int idx = blockIdx.x * 256 + threadIdx.x;
  const int nwc1 = NG * K1, nwc2 = NG * K2, nw2b = 128 * 512, nbi = 2 * NG;
  const int nfh = B * H, nxj = T * B, nctl = 512;
  if (idx < nwc1) {
    int n = idx / K1, col = idx - n * K1;
    int src = (n & 3) * H + (n >> 2);
    float v = (col < 63) ? Wihc[src * 63 + col]
            : (col == 63 ? 0.f : Whhc[src * 512 + (col - 64)]);
    __hip_bfloat16 h = bhi(v);
    wc1[n * K1 + col] = h; wc1l[n * K1 + col] = blo(v, h);
    return;
  }
  idx -= nwc1;
  if (idx < nwc2) {
    int n = idx / K2, col = idx - n * K2;
    int src = (n & 3) * H + (n >> 2);
    float v;
    if (col < 63)       v = Wihl[src * 575 + col];
    else if (col == 63) v = 0.f;
    else if (col < 576) v = Wihl[src * 575 + (col - 1)];
    else                v = Whhl[src * 512 + (col - 576)];
    __hip_bfloat16 h = bhi(v);
    wc2[n * K2 + col] = h; wc2l[n * K2 + col] = blo(v, h);
    return;
  }
  idx -= nwc2;
  if (idx < nw2b) {
    int n = idx >> 9, col = idx & 511;
    w2b[idx] = bhi(n < OUTW ? W2[n * 512 + col] : 0.f);
    return;
  }
  idx -= nw2b;
  if (idx < nbi) {
    int n = idx & (NG - 1);
    int src = (n & 3) * H + (n >> 2);
    if (idx < NG) bi1[n] = bc[src]; else bi2[n] = bl[src];
    return;
  }
  idx -= nbi;
  if (idx < nfh) {  // slot0 h1 init (hi+lo)
    int b = idx >> 9, j = idx & 511;
    float v = h1h[idx];
    __hip_bfloat16 h = bhi(v);
    fxHL[b * SLOTW + 64 + j] = h;
    fxHL[b * SLOTW + LOOF + 64 + j] = blo(v, h);
    return;
  }
  idx -= nfh;
  if (idx < nfh) {  // slot1 h2 init (hi only)
    int b = idx >> 9, j = idx & 511;
    fxHL[(size_t)SLOTE + b * SLOTW + 576 + j] = bhi(h2h[idx]);
    return;
  }
  idx -= nfh;
  if (idx < nxj) {  // x cols {0,1} hi + lo zeros for slot t+1
    int t = idx >> 7, b = idx & 127;
    float x0 = x[(b * T + t) * 3 + 0], x1 = x[(b * T + t) * 3 + 1];
    unsigned int* ph = (unsigned int*)(fxHL + (size_t)(t + 1) * SLOTE + b * SLOTW);
    ph[0] = pack2(x0, x1);
    unsigned int* pl = (unsigned int*)(fxHL + (size_t)(t + 1) * SLOTE + b * SLOTW + LOOF);
    pl[0] = 0u;
    return;
  }
  idx -= nxj;
  if (idx < nctl) ctl[idx] = 0;
}

// ---------------- MFMA helpers (A rows in fxHL slots, W in LDS) ----------------
template <int KWP>
DEVFN void gemm3(int tid, const __hip_bfloat16* __restrict__ Aslot, int m0,
                 const __hip_bfloat16* __restrict__ Wh, const __hip_bfloat16* __restrict__ Wl,
                 int cbeg, int cend, floatx4& a0, floatx4& a1)
{
  const int lane = tid & 63, wv = tid >> 6;
  const int lm = lane & 15, lk = (lane >> 4) << 3;
  const __hip_bfloat16* Ar = Aslot + (size_t)(m0 + wv * 16 + lm) * SLOTW;
  const __hip_bfloat16* W0h = Wh + lm * KWP;
  const __hip_bfloat16* W1h = Wh + (16 + lm) * KWP;
  const __hip_bfloat16* W0l = Wl + lm * KWP;
  const __hip_bfloat16* W1l = Wl + (16 + lm) * KWP;
  #pragma unroll 4
  for (int c = cbeg; c < cend; ++c) {
    int col = c * 32 + lk;
    short8 va  = *(const short8*)(Ar + col);
    short8 ua  = *(const short8*)(Ar + LOOF + col);
    short8 vb0 = *(const short8*)(W0h + col);
    short8 vb1 = *(const short8*)(W1h + col);
    short8 ub0 = *(const short8*)(W0l + col);
    short8 ub1 = *(const short8*)(W1l + col);
    a0 = __builtin_amdgcn_mfma_f32_16x16x32_bf16(va, vb0, a0, 0, 0, 0);
    a1 = __builtin_amdgcn_mfma_f32_16x16x32_bf16(va, vb1, a1, 0, 0, 0);
    a0 = __builtin_amdgcn_mfma_f32_16x16x32_bf16(va, ub0, a0, 0, 0, 0);
    a1 = __builtin_amdgcn_mfma_f32_16x16x32_bf16(va, ub1, a1, 0, 0, 0);
    a0 = __builtin_amdgcn_mfma_f32_16x16x32_bf16(ua, vb0, a0, 0, 0, 0);
    a1 = __builtin_amdgcn_mfma_f32_16x16x32_bf16(ua, vb1, a1, 0, 0, 0);
  }
}

template <int KWP>
DEVFN void gemm2(int tid, const __hip_bfloat16* __restrict__ Aslot, int m0,
                 const __hip_bfloat16* __restrict__ Wh, const __hip_bfloat16* __restrict__ Wl,
                 int cbeg, int cend, floatx4& a0, floatx4& a1)
{
  const int lane = tid & 63, wv = tid >> 6;
  const int lm = lane & 15, lk = (lane >> 4) << 3;
  const __hip_bfloat16* Ar = Aslot + (size_t)(m0 + wv * 16 + lm) * SLOTW;
  const __hip_bfloat16* W0h = Wh + lm * KWP;
  const __hip_bfloat16* W1h = Wh + (16 + lm) * KWP;
  const __hip_bfloat16* W0l = Wl + lm * KWP;
  const __hip_bfloat16* W1l = Wl + (16 + lm) * KWP;
  #pragma unroll 4
  for (int c = cbeg; c < cend; ++c) {
    int col = c * 32 + lk;
    short8 va  = *(const short8*)(Ar + col);
    short8 vb0 = *(const short8*)(W0h + col);
    short8 vb1 = *(const short8*)(W1h + col);
    short8 ub0 = *(const short8*)(W0l + col);
    short8 ub1 = *(const short8*)(W1l + col);
    a0 = __builtin_amdgcn_mfma_f32_16x16x32_bf16(va, vb0, a0, 0, 0, 0);
    a1 = __builtin_amdgcn_mfma_f32_16x16x32_bf16(va, vb1, a1, 0, 0, 0);
    a0 = __builtin_amdgcn_mfma_f32_16x16x32_bf16(va, ub0, a0, 0, 0, 0);
    a1 = __builtin_amdgcn_mfma_f32_16x16x32_bf16(va, ub1, a1, 0, 0, 0);
  }
}

DEVFN void store_gsm(int tid, float* Gsm, floatx4 a0, floatx4 a1) {
  const int lane = tid & 63, wv = tid >> 6;
  const int lm = lane & 15, rr = (lane >> 4) << 2;
  #pragma unroll
  for (int r = 0; r < 4; ++r) {
    Gsm[lm * 65 + wv * 16 + rr + r]        = a0[r];
    Gsm[(16 + lm) * 65 + wv * 16 + rr + r] = a1[r];
  }
}

// ---------------- persistent fused kernel ----------------
__global__ __launch_bounds__(256, 1) void k_persist(
    __hip_bfloat16* __restrict__ fxHL,
    const __hip_bfloat16* __restrict__ wc1, const __hip_bfloat16* __restrict__ wc1l,
    const __hip_bfloat16* __restrict__ wc2, const __hip_bfloat16* __restrict__ wc2l,
    const float* __restrict__ bi1, const float* __restrict__ bi2,
    const float* __restrict__ c1init, const float* __restrict__ c2init,
    const float* __restrict__ xin, const float* __restrict__ sent,
    const float* __restrict__ W1, const float* __restrict__ b1,
    int* __restrict__ ctl,
    float* __restrict__ h1f, float* __restrict__ c1f,
    float* __restrict__ h2f, float* __restrict__ c2f)
{
  extern __shared__ char sm[];
  const int gid = blockIdx.x, tid = threadIdx.x;
  int* ctrA = ctl;          // [half] at stride 32
  int* ctrB = ctl + 64;
  int* ctr2 = ctl + 128;

  if (gid < 128) {
    // ========== G1: window + lstm1 ==========
    const int nt1 = gid >> 1, mh = gid & 1;
    const int n0 = nt1 * 32, m0 = mh * 64;
    const int brow = mh * 64 + nt1;
    __hip_bfloat16* smWh = (__hip_bfloat16*)(sm + O_WH1);
    __hip_bfloat16* smWl = (__hip_bfloat16*)(sm + O_WL1);
    float* smW1 = (float*)(sm + O_W1S);
    float* Gsm  = (float*)(sm + O_GSM);
    float* hs   = (float*)(sm + O_HS);
    float* winv = (float*)(sm + O_HS);   // reused after hs is dead
    float* pp   = (float*)(sm + O_PP);
    float* ipl  = (float*)(sm + O_IPL);
    float* kl   = (float*)(sm + O_KL);
    float* phl  = (float*)(sm + O_PHL);
    float* wac  = (float*)(sm + O_WAC);
    float* kpr  = (float*)(sm + O_KPR);
    float* b1s  = (float*)(sm + O_B1S);
    float* bia  = (float*)(sm + O_BIA);

    for (int i = tid; i < 32 * 72; i += 256) {
      int r = i / 72, c8 = (i - r * 72) * 8;
      *(short8*)(smWh + r * KW1P + c8) = *(const short8*)(wc1  + (size_t)(n0 + r) * K1 + c8);
      *(short8*)(smWl + r * KW1P + c8) = *(const short8*)(wc1l + (size_t)(n0 + r) * K1 + c8);
    }
    for (int i = tid; i < 30 * 512; i += 256) {
      int j = i >> 9, c = i & 511;
      smW1[j * 520 + (c >> 6) * 65 + (c & 63)] = W1[i];
    }
    if (tid < 30) b1s[tid] = b1[tid];
    if (tid < 10) kpr[tid] = 0.f;
    if (tid < 32) bia[tid] = bi1[n0 + tid];
    __syncthreads();

    float creg[2];
    {
      int ml = tid >> 2, ppi = tid & 3;
      creg[0] = c1init[(m0 + ml) * H + nt1 * 8 + 2 * ppi + 0];
      creg[1] = c1init[(m0 + ml) * H + nt1 * 8 + 2 * ppi + 1];
    }

    for (int t = 0; t < T; ++t) {
      __hip_bfloat16* S1 = fxHL + (size_t)(t + 1) * SLOTE;
      __hip_bfloat16* S0 = fxHL + (size_t)t * SLOTE;

      // ---- window(t) for brow: h1_{t-1} = hi+lo from slot t ----
      for (int i = tid; i < 512; i += 256) {
        float hv = bf2f(S0[brow * SLOTW + 64 + i]) + bf2f(S0[brow * SLOTW + LOOF + 64 + i]);
        hs[(i >> 6) * 66 + (i & 63)] = hv;
      }
      __syncthreads();
      if (tid < 240) {
        int j = tid >> 3, p = tid & 7;
        const float* wp = smW1 + j * 520 + p * 65;
        const float* hv = hs + p * 66;
        float s = 0.f;
        #pragma unroll 8
        for (int k = 0; k < 64; ++k) s += hv[k] * wp[k];
        pp[tid] = s;
      }
      __syncthreads();
      if (tid < 30) {
        float s = b1s[tid];
        #pragma unroll
        for (int p = 0; p < 8; ++p) s += pp[tid * 8 + p];
        ipl[tid] = expf(s);
      }
      __syncthreads();
      if (tid < 10) {
        float kap = ipl[20 + tid] - kpr[tid];
        kpr[tid] = kap; kl[tid] = kap;
      }
      __syncthreads();
      if (tid < 64) {
        float u = (float)(tid + 1);
        float acc = 0.f;
        #pragma unroll
        for (int k = 0; k < 10; ++k) {
          float d = kl[k] - u;
          acc += ipl[k] * expf(-ipl[10 + k] * d * d);
        }
        phl[tid] = acc;
      }
      __syncthreads();
      if (tid < 240) {
        int c = tid >> 2, p = tid & 3;
        float acc = 0.f;
        #pragma unroll
        for (int s0 = 0; s0 < 16; ++s0)
          acc += phl[p * 16 + s0] * sent[(brow * 64 + p * 16 + s0) * 60 + c];
        wac[tid] = acc;
      }
      __syncthreads();
      if (tid < 60)
        winv[tid] = wac[tid * 4] + wac[tid * 4 + 1] + wac[tid * 4 + 2] + wac[tid * 4 + 3];
      __syncthreads();
      if (tid < 31) {  // publish win (dwords 1..31 of hi and lo line-0 region)
        int d = 1 + tid;
        int c0 = 2 * d, c1 = 2 * d + 1;
        float v0 = (c0 == 2) ? xin[(brow * T + t) * 3 + 2] : winv[c0 - 3];
        float v1 = (c1 == 63) ? 0.f : winv[c1 - 3];
        __hip_bfloat16 h0 = bhi(v0), h1v = bhi(v1);
        unsigned int* prow = (unsigned int*)(S1 + brow * SLOTW);
        ast(prow + d, (unsigned int)bbits(h0) | ((unsigned int)bbits(h1v) << 16));
        ast(prow + (LOOF >> 1) + d,
            (unsigned int)bbits(blo(v0, h0)) | ((unsigned int)bbits(blo(v1, h1v)) << 16));
      }
      gbar(&ctrA[mh * 32], 64 * (t + 1));   // all win published in half

      // ---- gate GEMM: chunks 0..1 from slot t+1 (x,win), 2..17 from slot t (h1) ----
      floatx4 a0 = {0.f, 0.f, 0.f, 0.f}, a1 = a0;
      gemm3<KW1P>(tid, S1, m0, smWh, smWl, 0, 2, a0, a1);
      gemm3<KW1P>(tid, S0, m0, smWh, smWl, 2, K1C, a0, a1);
      store_gsm(tid, Gsm, a0, a1);
      __syncthreads();

      // ---- epilogue: each thread 2 adjacent h-cols of one m-row ----
      {
        int ml = tid >> 2, ppi = tid & 3;
        float v[2];
        #pragma unroll
        for (int j = 0; j < 2; ++j) {
          int nl = ppi * 8 + j * 4;
          float gi = Gsm[(nl + 0) * 65 + ml] + bia[nl + 0];
          float gf = Gsm[(nl + 1) * 65 + ml] + bia[nl + 1];
          float gg = Gsm[(nl + 2) * 65 + ml] + bia[nl + 2];
          float go = Gsm[(nl + 3) * 65 + ml] + bia[nl + 3];
          float ig = 1.f / (1.f + expf(-gi));
          float fg = 1.f / (1.f + expf(-gf));
          float gt = tanhf(gg);
          float og = 1.f / (1.f + expf(-go));
          float cn = fg * creg[j] + ig * gt;
          v[j] = og * tanhf(cn);
          creg[j] = cn;
        }
        __hip_bfloat16 h0 = bhi(v[0]), h1v = bhi(v[1]);
        unsigned int* prow = (unsigned int*)(S1 + (m0 + ml) * SLOTW);
        int dw = 32 + nt1 * 4 + ppi;       // hi dword of cols {64+nt1*8+2p, +1}
        ast(prow + dw, (unsigned int)bbits(h0) | ((unsigned int)bbits(h1v) << 16));
        ast(prow + (LOOF >> 1) + dw,
            (unsigned int)bbits(blo(v[0], h0)) | ((unsigned int)bbits(blo(v[1], h1v)) << 16));
        if (t == T - 1) {
          int hg = nt1 * 8 + 2 * ppi;
          h1f[(m0 + ml) * H + hg]     = v[0];  c1f[(m0 + ml) * H + hg]     = creg[0];
          h1f[(m0 + ml) * H + hg + 1] = v[1];  c1f[(m0 + ml) * H + hg + 1] = creg[1];
        }
      }
      gbar(&ctrB[mh * 32], 64 * (t + 1));   // h1_t published
    }
  } else {
    // ========== G2: lstm2 ==========
    const int g = gid - 128;
    const int nt2 = g >> 1, mh = g & 1;
    const int n0 = nt2 * 32, m0 = mh * 64;
    __hip_bfloat16* smWh = (__hip_bfloat16*)(sm + O_WH2);
    __hip_bfloat16* smWl = (__hip_bfloat16*)(sm + O_WL2);
    float* Gsm = (float*)(sm + O_GS2);
    float* bia = (float*)(sm + O_BI2);

    for (int i = tid; i < 32 * 136; i += 256) {
      int r = i / 136, c8 = (i - r * 136) * 8;
      *(short8*)(smWh + r * KW2P + c8) = *(const short8*)(wc2  + (size_t)(n0 + r) * K2 + c8);
      *(short8*)(smWl + r * KW2P + c8) = *(const short8*)(wc2l + (size_t)(n0 + r) * K2 + c8);
    }
    if (tid < 32) bia[tid] = bi2[n0 + tid];
    __syncthreads();

    float creg[2];
    {
      int ml = tid >> 2, ppi = tid & 3;
      creg[0] = c2init[(m0 + ml) * H + nt2 * 8 + 2 * ppi + 0];
      creg[1] = c2init[(m0 + ml) * H + nt2 * 8 + 2 * ppi + 1];
    }

    for (int t = 0; t < T; ++t) {
      __hip_bfloat16* S1 = fxHL + (size_t)(t + 1) * SLOTE;
      __hip_bfloat16* S2 = fxHL + (size_t)(t + 2) * SLOTE;

      floatx4 a0 = {0.f, 0.f, 0.f, 0.f}, a1 = a0;
      // h2 recurrent part first (depends only on own previous step), hi-A x2
      gemm2<KW2P>(tid, S1, m0, smWh, smWl, K1C, K2C, a0, a1);
      // wait for lstm1 half: win_t + h1_t in slot t+1
      waitge(&ctrB[mh * 32], 64 * (t + 1));
      gemm3<KW2P>(tid, S1, m0, smWh, smWl, 0, K1C, a0, a1);
      store_gsm(tid, Gsm, a0, a1);
      __syncthreads();

      {
        int ml = tid >> 2, ppi = tid & 3;
        float v[2];
        #pragma unroll
        for (int j = 0; j < 2; ++j) {
          int nl = ppi * 8 + j * 4;
          float gi = Gsm[(nl + 0) * 65 + ml] + bia[nl + 0];
          float gf = Gsm[(nl + 1) * 65 + ml] + bia[nl + 1];
          float gg = Gsm[(nl + 2) * 65 + ml] + bia[nl + 2];
          float go = Gsm[(nl + 3) * 65 + ml] + bia[nl + 3];
          float ig = 1.f / (1.f + expf(-gi));
          float fg = 1.f / (1.f + expf(-gf));
          float gt = tanhf(gg);
          float og = 1.f / (1.f + expf(-go));
          float cn = fg * creg[j] + ig * gt;
          v[j] = og * tanhf(cn);
          creg[j] = cn;
        }
        __hip_bfloat16 h0 = bhi(v[0]), h1v = bhi(v[1]);
        unsigned int* prow = (unsigned int*)(S2 + (m0 + ml) * SLOTW);
        int dw = 288 + nt2 * 4 + ppi;      // hi dword of cols {576+nt2*8+2p, +1}
        ast(prow + dw, (unsigned int)bbits(h0) | ((unsigned int)bbits(h1v) << 16));
        if (t == T - 1) {
          int hg = nt2 * 8 + 2 * ppi;
          h2f[(m0 + ml) * H + hg]     = v[0];  c2f[(m0 + ml) * H + hg]     = creg[0];
          h2f[(m0 + ml) * H + hg + 1] = v[1];  c2f[(m0 + ml) * H + hg + 1] = creg[1];
        }
      }
      gbar(&ctr2[mh * 32], 64 * (t + 1));   // h2_t published in half
    }
  }
}

// ---------------- final GEMM: out[BT x 121] = h2 @ W2^T + b2 ----------------
__global__ __launch_bounds__(256) void k_out(
    const __hip_bfloat16* __restrict__ fxHL, const __hip_bfloat16* __restrict__ w2b,
    const float* __restrict__ b2, float* __restrict__ dout)
{
  int bid = blockIdx.x, tid = threadIdx.x;
  int mblk = bid >> 1, nblk = bid & 1;
  int wv = tid >> 6, lane = tid & 63;
  int lm = lane & 15, lk = (lane >> 4) << 3;
  int m0 = mblk * 128 + wv * 32;
  int n0 = nblk * 64;
  int r0 = m0 + lm, r1 = m0 + 16 + lm;
  const __hip_bfloat16* a0p = fxHL + (size_t)((r0 & 255) + 2) * SLOTE + (r0 >> 8) * SLOTW + 576;
  const __hip_bfloat16* a1p = fxHL + (size_t)((r1 & 255) + 2) * SLOTE + (r1 >> 8) * SLOTW + 576;
  floatx4 zz = {0.f, 0.f, 0.f, 0.f};
  floatx4 acc[2][4];
  #pragma unroll
  for (int mt = 0; mt < 2; ++mt)
    #pragma unroll
    for (int nt = 0; nt < 4; ++nt) acc[mt][nt] = zz;
  #pragma unroll
  for (int c = 0; c < 16; ++c) {
    int col = c * 32 + lk;
    short8 va0 = *(const short8*)(a0p + col);
    short8 va1 = *(const short8*)(a1p + col);
    short8 vb[4];
    #pragma unroll
    for (int nt = 0; nt < 4; ++nt)
      vb[nt] = *(const short8*)(w2b + (size_t)(n0 + nt * 16 + lm) * 512 + col);
    #pragma unroll
    for (int nt = 0; nt < 4; ++nt) {
      acc[0][nt] = __builtin_amdgcn_mfma_f32_16x16x32_bf16(va0, vb[nt], acc[0][nt], 0, 0, 0);
      acc[1][nt] = __builtin_amdgcn_mfma_f32_16x16x32_bf16(va1, vb[nt], acc[1][nt], 0, 0, 0);
    }
  }
  int rr = (lane >> 4) << 2;
  #pragma unroll
  for (int mt = 0; mt < 2; ++mt)
    #pragma unroll
    for (int nt = 0; nt < 4; ++nt)
      #pragma unroll
      for (int r = 0; r < 4; ++r) {
        int m = m0 + mt * 16 + rr + r;
        int n = n0 + nt * 16 + lm;
        if (n < OUTW) dout[(size_t)m * OUTW + n] = acc[mt][nt][r] + b2[n];
      }
}

// ---------------- host ----------------
extern "C" void kernel_launch(void* const* d_in, const int* in_sizes, int n_in,
                              void* d_out, int out_size, void* d_ws, size_t ws_size,
                              hipStream_t stream)
{
  (void)in_sizes; (void)n_in; (void)out_size; (void)ws_size;
  const float* x    = (const float*)d_in[0];
  const float* sent = (const float*)d_in[1];
  const float* h1h  = (const float*)d_in[2];
  const float* h1c  = (const float*)d_in[3];
  const float* h2h  = (const float*)d_in[4];
  const float* h2c  = (const float*)d_in[5];
  const float* Wihc = (const float*)d_in[6];
  const float* Whhc = (const float*)d_in[7];
  const float* bc   = (const float*)d_in[8];
  const float* Wihl = (const float*)d_in[9];
  const float* Whhl = (const float*)d_in[10];
  const float* bl   = (const float*)d_in[11];
  const float* W1   = (const float*)d_in[12];
  const float* b1   = (const float*)d_in[13];
  const float* W2   = (const float*)d_in[14];
  const float* b2   = (const float*)d_in[15];

  float* out = (float*)d_out;
  float* h1f = out + (size_t)B * T * OUTW;
  float* c1f = h1f + (size_t)B * H;
  float* h2f = c1f + (size_t)B * H;
  float* c2f = h2f + (size_t)B * H;

  char* p = (char*)d_ws;
  auto carve = [&](size_t bytes) { char* r = p; p += (bytes + 255) & ~(size_t)255; return r; };
  __hip_bfloat16* fxHL = (__hip_bfloat16*)carve((size_t)NSLOT * SLOTE * 2);
  __hip_bfloat16* wc1  = (__hip_bfloat16*)carve((size_t)NG * K1 * 2);
  __hip_bfloat16* wc1l = (__hip_bfloat16*)carve((size_t)NG * K1 * 2);
  __hip_bfloat16* wc2  = (__hip_bfloat16*)carve((size_t)NG * K2 * 2);
  __hip_bfloat16* wc2l = (__hip_bfloat16*)carve((size_t)NG * K2 * 2);
  __hip_bfloat16* w2b  = (__hip_bfloat16*)carve((size_t)128 * 512 * 2);
  float* bi1 = (float*)carve((size_t)NG * 4);
  float* bi2 = (float*)carve((size_t)NG * 4);
  int*   ctl = (int*)carve((size_t)512 * 4);

  static bool attr_set = false;
  if (!attr_set) {
    (void)hipFuncSetAttribute((const void*)k_persist,
                              hipFuncAttributeMaxDynamicSharedMemorySize, LDS_SZ);
    attr_set = true;
  }

  k_pre<<<14226, 256, 0, stream>>>(x, h1h, h2h, Wihc, Whhc, bc, Wihl, Whhl, bl, W2,
                                   fxHL, wc1, wc1l, wc2, wc2l, w2b, bi1, bi2, ctl);
  k_persist<<<256, 256, LDS_SZ, stream>>>(fxHL, wc1, wc1l, wc2, wc2l, bi1, bi2,
                                          h1c, h2c, x, sent, W1, b1, ctl,
                                          h1f, c1f, h2f, c2f);
  k_out<<<512, 256, 0, stream>>>(fxHL, w2b, b2, out);
}

// Round 6
// 3328.483 us; speedup vs baseline: 4.9032x; 1.0582x over previous
//
#include <hip/hip_runtime.h>
#include <hip/hip_bf16.h>
#include <math.h>

typedef __attribute__((ext_vector_type(8))) short short8;
typedef __attribute__((ext_vector_type(4))) float floatx4;

#define DEVFN static __device__ __forceinline__

constexpr int B = 128, T = 256, H = 512;
constexpr int OUTW = 121;
// fxHL slot row layout (per batch row, per time slot), elems:
//   hi: [x(3) win(60) pad(1) h1(512) h2(512)] = 1088
//   lo: cols 0..575 only (x,win,h1)           = 576
constexpr int SLOTW = 1664;              // row stride in elems (hi 1088 + lo 576)
constexpr int LOOF  = 1088;              // lo region offset within row
constexpr int SLOTE = B * SLOTW;         // elems per time slot
constexpr int NSLOT = T + 2;
constexpr int NG  = 2048;                // 4*H gate rows (interleaved n' = hcol*4+gate)
constexpr int K1  = 576,  K1C = 18;
constexpr int K2  = 1088, K2C = 34;
constexpr int KW1P = 584, KW2P = 1096;   // LDS weight row pads

// ---- LDS offsets (bytes) ----
constexpr int O_WH1 = 0;                 // 32*584*2
constexpr int O_WL1 = 37376;
constexpr int O_W1S = 74752;             // 30*520*4
constexpr int O_GSM = 137152;            // 32*65*4
constexpr int O_HS  = 145472;            // 528*4 (reused as winv[60] later)
constexpr int O_PP  = 147584;            // 240*4
constexpr int O_IPL = 148544;            // 30*4
constexpr int O_KL  = 148664;
constexpr int O_PHL = 148704;            // 64*4
constexpr int O_WAC = 148960;            // 240*4
constexpr int O_KPR = 149920;
constexpr int O_B1S = 149960;
constexpr int O_BIA = 150080;            // 32*4
constexpr int O_WH2 = 0;                 // 32*1096*2
constexpr int O_WL2 = 70144;
constexpr int O_GS2 = 140288;
constexpr int O_BI2 = 148608;
constexpr int LDS_SZ = 150272;

DEVFN __hip_bfloat16 bhi(float v) { return __float2bfloat16(v); }
DEVFN __hip_bfloat16 blo(float v, __hip_bfloat16 h) { return __float2bfloat16(v - __bfloat162float(h)); }
DEVFN float bf2f(__hip_bfloat16 h) { return __bfloat162float(h); }
DEVFN unsigned short bbits(__hip_bfloat16 h) { union { __hip_bfloat16 h; unsigned short u; } c; c.h = h; return c.u; }
DEVFN unsigned int pack2(float a, float b) {
  return (unsigned int)bbits(bhi(a)) | ((unsigned int)bbits(bhi(b)) << 16);
}
DEVFN void ast(unsigned int* p, unsigned int v) {
  __hip_atomic_store(p, v, __ATOMIC_RELAXED, __HIP_MEMORY_SCOPE_AGENT);
}
DEVFN int ald(int* p) {
  return __hip_atomic_load(p, __ATOMIC_RELAXED, __HIP_MEMORY_SCOPE_AGENT);
}

// wait until flags[i] >= target for i in [0,n) (n<=256); parallel per-flag polls
DEVFN void waitflags(int* flags, int n, int target) {
  if ((int)threadIdx.x < n) {
    int g = 0;
    while (ald(&flags[threadIdx.x]) < target && g < (1 << 22)) { ++g; __builtin_amdgcn_s_sleep(1); }
  }
  __syncthreads();
}
// wait on two 64-flag arrays
DEVFN void dualwait(int* fa, int* fb, int target) {
  int tid = threadIdx.x;
  if (tid < 128) {
    int* f = (tid < 64) ? fa + tid : fb + (tid - 64);
    int g = 0;
    while (ald(f) < target && g < (1 << 22)) { ++g; __builtin_amdgcn_s_sleep(1); }
  }
  __syncthreads();
}
// drain own stores, then publish flag value (single store, no atomic RMW)
DEVFN void flag_store(int* flag, int val) {
  asm volatile("s_waitcnt vmcnt(0)" ::: "memory");
  __syncthreads();
  if (threadIdx.x == 0)
    __hip_atomic_store(flag, val, __ATOMIC_RELAXED, __HIP_MEMORY_SCOPE_AGENT);
}

// ---------------- precompute ----------------
__global__ __launch_bounds__(256) void k_pre(
    const float* __restrict__ x, const float* __restrict__ h1h, const float* __restrict__ h2h,
    const float* __restrict__ Wihc, const float* __restrict__ Whhc, const float* __restrict__ bc,
    const float* __restrict__ Wihl, const float* __restrict__ Whhl, const float* __restrict__ bl,
    const float* __restrict__ W2,
    __hip_bfloat16* __restrict__ fxHL,
    __hip_bfloat16* __restrict__ wc1, __hip_bfloat16* __restrict__ wc1l,
    __hip_bfloat16* __restrict__ wc2, __hip_bfloat16* __restrict__ wc2l,
    __hip_bfloat16* __restrict__ w2b, float* __restrict__ bi1, float* __restrict__ bi2,
    int* __restrict__ ctl)
{
  int idx = blockIdx.x * 256 + threadIdx.x;
  const int nwc1 = NG * K1, nwc2 = NG * K2, nw2b = 128 * 512, nbi = 2 * NG;
  const int nfh = B * H, nxj = T * B, nctl = 512;
  if (idx < nwc1) {
    int n = idx / K1, col = idx - n * K1;
    int src = (n & 3) * H + (n >> 2);
    float v = (col < 63) ? Wihc[src * 63 + col]
            : (col == 63 ? 0.f : Whhc[src * 512 + (col - 64)]);
    __hip_bfloat16 h = bhi(v);
    wc1[n * K1 + col] = h; wc1l[n * K1 + col] = blo(v, h);
    return;
  }
  idx -= nwc1;
  if (idx < nwc2) {
    int n = idx / K2, col = idx - n * K2;
    int src = (n & 3) * H + (n >> 2);
    float v;
    if (col < 63)       v = Wihl[src * 575 + col];
    else if (col == 63) v = 0.f;
    else if (col < 576) v = Wihl[src * 575 + (col - 1)];
    else                v = Whhl[src * 512 + (col - 576)];
    __hip_bfloat16 h = bhi(v);
    wc2[n * K2 + col] = h; wc2l[n * K2 + col] = blo(v, h);
    return;
  }
  idx -= nwc2;
  if (idx < nw2b) {
    int n = idx >> 9, col = idx & 511;
    w2b[idx] = bhi(n < OUTW ? W2[n * 512 + col] : 0.f);
    return;
  }
  idx -= nw2b;
  if (idx < nbi) {
    int n = idx & (NG - 1);
    int src = (n & 3) * H + (n >> 2);
    if (idx < NG) bi1[n] = bc[src]; else bi2[n] = bl[src];
    return;
  }
  idx -= nbi;
  if (idx < nfh) {  // slot0 h1 init (hi+lo)
    int b = idx >> 9, j = idx & 511;
    float v = h1h[idx];
    __hip_bfloat16 h = bhi(v);
    fxHL[b * SLOTW + 64 + j] = h;
    fxHL[b * SLOTW + LOOF + 64 + j] = blo(v, h);
    return;
  }
  idx -= nfh;
  if (idx < nfh) {  // slot1 h2 init (hi only)
    int b = idx >> 9, j = idx & 511;
    fxHL[(size_t)SLOTE + b * SLOTW + 576 + j] = bhi(h2h[idx]);
    return;
  }
  idx -= nfh;
  if (idx < nxj) {  // x cols {0,1} hi + lo zeros for slot t+1
    int t = idx >> 7, b = idx & 127;
    float x0 = x[(b * T + t) * 3 + 0], x1 = x[(b * T + t) * 3 + 1];
    unsigned int* ph = (unsigned int*)(fxHL + (size_t)(t + 1) * SLOTE + b * SLOTW);
    ph[0] = pack2(x0, x1);
    unsigned int* pl = (unsigned int*)(fxHL + (size_t)(t + 1) * SLOTE + b * SLOTW + LOOF);
    pl[0] = 0u;
    return;
  }
  idx -= nxj;
  if (idx < nctl) ctl[idx] = 0;
}

// ---------------- MFMA helpers (A rows in fxHL slots, W in LDS) ----------------
template <int KWP>
DEVFN void gemm3(int tid, const __hip_bfloat16* __restrict__ Aslot, int m0,
                 const __hip_bfloat16* __restrict__ Wh, const __hip_bfloat16* __restrict__ Wl,
                 int cbeg, int cend, floatx4& a0, floatx4& a1)
{
  const int lane = tid & 63, wv = tid >> 6;
  const int lm = lane & 15, lk = (lane >> 4) << 3;
  const __hip_bfloat16* Ar = Aslot + (size_t)(m0 + wv * 16 + lm) * SLOTW;
  const __hip_bfloat16* W0h = Wh + lm * KWP;
  const __hip_bfloat16* W1h = Wh + (16 + lm) * KWP;
  const __hip_bfloat16* W0l = Wl + lm * KWP;
  const __hip_bfloat16* W1l = Wl + (16 + lm) * KWP;
  #pragma unroll 4
  for (int c = cbeg; c < cend; ++c) {
    int col = c * 32 + lk;
    short8 va  = *(const short8*)(Ar + col);
    short8 ua  = *(const short8*)(Ar + LOOF + col);
    short8 vb0 = *(const short8*)(W0h + col);
    short8 vb1 = *(const short8*)(W1h + col);
    short8 ub0 = *(const short8*)(W0l + col);
    short8 ub1 = *(const short8*)(W1l + col);
    a0 = __builtin_amdgcn_mfma_f32_16x16x32_bf16(va, vb0, a0, 0, 0, 0);
    a1 = __builtin_amdgcn_mfma_f32_16x16x32_bf16(va, vb1, a1, 0, 0, 0);
    a0 = __builtin_amdgcn_mfma_f32_16x16x32_bf16(va, ub0, a0, 0, 0, 0);
    a1 = __builtin_amdgcn_mfma_f32_16x16x32_bf16(va, ub1, a1, 0, 0, 0);
    a0 = __builtin_amdgcn_mfma_f32_16x16x32_bf16(ua, vb0, a0, 0, 0, 0);
    a1 = __builtin_amdgcn_mfma_f32_16x16x32_bf16(ua, vb1, a1, 0, 0, 0);
  }
}

template <int KWP>
DEVFN void gemm2(int tid, const __hip_bfloat16* __restrict__ Aslot, int m0,
                 const __hip_bfloat16* __restrict__ Wh, const __hip_bfloat16* __restrict__ Wl,
                 int cbeg, int cend, floatx4& a0, floatx4& a1)
{
  const int lane = tid & 63, wv = tid >> 6;
  const int lm = lane & 15, lk = (lane >> 4) << 3;
  const __hip_bfloat16* Ar = Aslot + (size_t)(m0 + wv * 16 + lm) * SLOTW;
  const __hip_bfloat16* W0h = Wh + lm * KWP;
  const __hip_bfloat16* W1h = Wh + (16 + lm) * KWP;
  const __hip_bfloat16* W0l = Wl + lm * KWP;
  const __hip_bfloat16* W1l = Wl + (16 + lm) * KWP;
  #pragma unroll 4
  for (int c = cbeg; c < cend; ++c) {
    int col = c * 32 + lk;
    short8 va  = *(const short8*)(Ar + col);
    short8 vb0 = *(const short8*)(W0h + col);
    short8 vb1 = *(const short8*)(W1h + col);
    short8 ub0 = *(const short8*)(W0l + col);
    short8 ub1 = *(const short8*)(W1l + col);
    a0 = __builtin_amdgcn_mfma_f32_16x16x32_bf16(va, vb0, a0, 0, 0, 0);
    a1 = __builtin_amdgcn_mfma_f32_16x16x32_bf16(va, vb1, a1, 0, 0, 0);
    a0 = __builtin_amdgcn_mfma_f32_16x16x32_bf16(va, ub0, a0, 0, 0, 0);
    a1 = __builtin_amdgcn_mfma_f32_16x16x32_bf16(va, ub1, a1, 0, 0, 0);
  }
}

DEVFN void store_gsm(int tid, float* Gsm, floatx4 a0, floatx4 a1) {
  const int lane = tid & 63, wv = tid >> 6;
  const int lm = lane & 15, rr = (lane >> 4) << 2;
  #pragma unroll
  for (int r = 0; r < 4; ++r) {
    Gsm[lm * 65 + wv * 16 + rr + r]        = a0[r];
    Gsm[(16 + lm) * 65 + wv * 16 + rr + r] = a1[r];
  }
}

// ---------------- persistent fused kernel ----------------
__global__ __launch_bounds__(256, 1) void k_persist(
    __hip_bfloat16* __restrict__ fxHL,
    const __hip_bfloat16* __restrict__ wc1, const __hip_bfloat16* __restrict__ wc1l,
    const __hip_bfloat16* __restrict__ wc2, const __hip_bfloat16* __restrict__ wc2l,
    const float* __restrict__ bi1, const float* __restrict__ bi2,
    const float* __restrict__ c1init, const float* __restrict__ c2init,
    const float* __restrict__ xin, const float* __restrict__ sent,
    const float* __restrict__ W1, const float* __restrict__ b1,
    int* __restrict__ ctl,
    float* __restrict__ h1f, float* __restrict__ c1f,
    float* __restrict__ h2f, float* __restrict__ c2f)
{
  extern __shared__ char sm[];
  const int gid = blockIdx.x, tid = threadIdx.x;
  // flag arrays: [half][64]
  // wflag: win published (by window-row block), h1flag: h1 published (per G1 block),
  // h2flag: h2 published (per G2 block)

  if (gid < 128) {
    // ========== G1: window + lstm1 ==========
    const int nt1 = gid >> 1, mh = gid & 1;
    const int n0 = nt1 * 32, m0 = mh * 64;
    const int brow = mh * 64 + nt1;
    int* wf = ctl + mh * 64;
    int* hf = ctl + 128 + mh * 64;
    __hip_bfloat16* smWh = (__hip_bfloat16*)(sm + O_WH1);
    __hip_bfloat16* smWl = (__hip_bfloat16*)(sm + O_WL1);
    float* smW1 = (float*)(sm + O_W1S);
    float* Gsm  = (float*)(sm + O_GSM);
    float* hs   = (float*)(sm + O_HS);
    float* winv = (float*)(sm + O_HS);   // reused after hs is dead
    float* pp   = (float*)(sm + O_PP);
    float* ipl  = (float*)(sm + O_IPL);
    float* kl   = (float*)(sm + O_KL);
    float* phl  = (float*)(sm + O_PHL);
    float* wac  = (float*)(sm + O_WAC);
    float* kpr  = (float*)(sm + O_KPR);
    float* b1s  = (float*)(sm + O_B1S);
    float* bia  = (float*)(sm + O_BIA);

    for (int i = tid; i < 32 * 72; i += 256) {
      int r = i / 72, c8 = (i - r * 72) * 8;
      *(short8*)(smWh + r * KW1P + c8) = *(const short8*)(wc1  + (size_t)(n0 + r) * K1 + c8);
      *(short8*)(smWl + r * KW1P + c8) = *(const short8*)(wc1l + (size_t)(n0 + r) * K1 + c8);
    }
    for (int i = tid; i < 30 * 512; i += 256) {
      int j = i >> 9, c = i & 511;
      smW1[j * 520 + (c >> 6) * 65 + (c & 63)] = W1[i];
    }
    if (tid < 30) b1s[tid] = b1[tid];
    if (tid < 10) kpr[tid] = 0.f;
    if (tid < 32) bia[tid] = bi1[n0 + tid];
    __syncthreads();

    float creg[2];
    {
      int ml = tid >> 2, ppi = tid & 3;
      creg[0] = c1init[(m0 + ml) * H + nt1 * 8 + 2 * ppi + 0];
      creg[1] = c1init[(m0 + ml) * H + nt1 * 8 + 2 * ppi + 1];
    }

    for (int t = 0; t < T; ++t) {
      __hip_bfloat16* S1 = fxHL + (size_t)(t + 1) * SLOTE;
      __hip_bfloat16* S0 = fxHL + (size_t)t * SLOTE;

      // all same-half h1_{t-1} published (also covers this block's window source row)
      waitflags(hf, 64, t);

      // ---- window(t) for brow: h1_{t-1} = hi+lo from slot t ----
      for (int i = tid; i < 512; i += 256) {
        float hv = bf2f(S0[brow * SLOTW + 64 + i]) + bf2f(S0[brow * SLOTW + LOOF + 64 + i]);
        hs[(i >> 6) * 66 + (i & 63)] = hv;
      }
      __syncthreads();
      if (tid < 240) {
        int j = tid >> 3, p = tid & 7;
        const float* wp = smW1 + j * 520 + p * 65;
        const float* hv = hs + p * 66;
        float s = 0.f;
        #pragma unroll 8
        for (int k = 0; k < 64; ++k) s += hv[k] * wp[k];
        pp[tid] = s;
      }
      __syncthreads();
      if (tid < 30) {
        float s = b1s[tid];
        #pragma unroll
        for (int p = 0; p < 8; ++p) s += pp[tid * 8 + p];
        ipl[tid] = expf(s);
      }
      __syncthreads();
      if (tid < 10) {
        float kap = ipl[20 + tid] - kpr[tid];
        kpr[tid] = kap; kl[tid] = kap;
      }
      __syncthreads();
      if (tid < 64) {
        float u = (float)(tid + 1);
        float acc = 0.f;
        #pragma unroll
        for (int k = 0; k < 10; ++k) {
          float d = kl[k] - u;
          acc += ipl[k] * expf(-ipl[10 + k] * d * d);
        }
        phl[tid] = acc;
      }
      __syncthreads();
      if (tid < 240) {
        int c = tid >> 2, p = tid & 3;
        float acc = 0.f;
        #pragma unroll
        for (int s0 = 0; s0 < 16; ++s0)
          acc += phl[p * 16 + s0] * sent[(brow * 64 + p * 16 + s0) * 60 + c];
        wac[tid] = acc;
      }
      __syncthreads();
      if (tid < 60)
        winv[tid] = wac[tid * 4] + wac[tid * 4 + 1] + wac[tid * 4 + 2] + wac[tid * 4 + 3];
      __syncthreads();
      if (tid < 31) {  // publish win (dwords 1..31 of hi and lo line-0 region)
        int d = 1 + tid;
        int c0 = 2 * d, c1 = 2 * d + 1;
        float v0 = (c0 == 2) ? xin[(brow * T + t) * 3 + 2] : winv[c0 - 3];
        float v1 = (c1 == 63) ? 0.f : winv[c1 - 3];
        __hip_bfloat16 h0 = bhi(v0), h1v = bhi(v1);
        unsigned int* prow = (unsigned int*)(S1 + brow * SLOTW);
        ast(prow + d, (unsigned int)bbits(h0) | ((unsigned int)bbits(h1v) << 16));
        ast(prow + (LOOF >> 1) + d,
            (unsigned int)bbits(blo(v0, h0)) | ((unsigned int)bbits(blo(v1, h1v)) << 16));
      }
      flag_store(wf + nt1, t + 1);          // win(brow) published

      // ---- h1-part GEMM first (needs only slot t) — hides win exchange ----
      floatx4 a0 = {0.f, 0.f, 0.f, 0.f}, a1 = a0;
      gemm3<KW1P>(tid, S0, m0, smWh, smWl, 2, K1C, a0, a1);
      waitflags(wf, 64, t + 1);             // all wins of this half available
      gemm3<KW1P>(tid, S1, m0, smWh, smWl, 0, 2, a0, a1);
      store_gsm(tid, Gsm, a0, a1);
      __syncthreads();

      // ---- epilogue: each thread 2 adjacent h-cols of one m-row ----
      {
        int ml = tid >> 2, ppi = tid & 3;
        float v[2];
        #pragma unroll
        for (int j = 0; j < 2; ++j) {
          int nl = ppi * 8 + j * 4;
          float gi = Gsm[(nl + 0) * 65 + ml] + bia[nl + 0];
          float gf = Gsm[(nl + 1) * 65 + ml] + bia[nl + 1];
          float gg = Gsm[(nl + 2) * 65 + ml] + bia[nl + 2];
          float go = Gsm[(nl + 3) * 65 + ml] + bia[nl + 3];
          float ig = 1.f / (1.f + expf(-gi));
          float fg = 1.f / (1.f + expf(-gf));
          float gt = tanhf(gg);
          float og = 1.f / (1.f + expf(-go));
          float cn = fg * creg[j] + ig * gt;
          v[j] = og * tanhf(cn);
          creg[j] = cn;
        }
        __hip_bfloat16 h0 = bhi(v[0]), h1v = bhi(v[1]);
        unsigned int* prow = (unsigned int*)(S1 + (m0 + ml) * SLOTW);
        int dw = 32 + nt1 * 4 + ppi;       // hi dword of cols {64+nt1*8+2p, +1}
        ast(prow + dw, (unsigned int)bbits(h0) | ((unsigned int)bbits(h1v) << 16));
        ast(prow + (LOOF >> 1) + dw,
            (unsigned int)bbits(blo(v[0], h0)) | ((unsigned int)bbits(blo(v[1], h1v)) << 16));
        if (t == T - 1) {
          int hg = nt1 * 8 + 2 * ppi;
          h1f[(m0 + ml) * H + hg]     = v[0];  c1f[(m0 + ml) * H + hg]     = creg[0];
          h1f[(m0 + ml) * H + hg + 1] = v[1];  c1f[(m0 + ml) * H + hg + 1] = creg[1];
        }
      }
      flag_store(hf + nt1, t + 1);          // h1 slice published
    }
  } else {
    // ========== G2: lstm2 ==========
    const int g = gid - 128;
    const int nt2 = g >> 1, mh = g & 1;
    const int n0 = nt2 * 32, m0 = mh * 64;
    int* wf  = ctl + mh * 64;
    int* hf  = ctl + 128 + mh * 64;
    int* h2g = ctl + 256 + mh * 64;
    __hip_bfloat16* smWh = (__hip_bfloat16*)(sm + O_WH2);
    __hip_bfloat16* smWl = (__hip_bfloat16*)(sm + O_WL2);
    float* Gsm = (float*)(sm + O_GS2);
    float* bia = (float*)(sm + O_BI2);

    for (int i = tid; i < 32 * 136; i += 256) {
      int r = i / 136, c8 = (i - r * 136) * 8;
      *(short8*)(smWh + r * KW2P + c8) = *(const short8*)(wc2  + (size_t)(n0 + r) * K2 + c8);
      *(short8*)(smWl + r * KW2P + c8) = *(const short8*)(wc2l + (size_t)(n0 + r) * K2 + c8);
    }
    if (tid < 32) bia[tid] = bi2[n0 + tid];
    __syncthreads();

    float creg[2];
    {
      int ml = tid >> 2, ppi = tid & 3;
      creg[0] = c2init[(m0 + ml) * H + nt2 * 8 + 2 * ppi + 0];
      creg[1] = c2init[(m0 + ml) * H + nt2 * 8 + 2 * ppi + 1];
    }

    for (int t = 0; t < T; ++t) {
      __hip_bfloat16* S1 = fxHL + (size_t)(t + 1) * SLOTE;
      __hip_bfloat16* S2 = fxHL + (size_t)(t + 2) * SLOTE;

      // own-half h2_{t-1} complete in S1
      waitflags(h2g, 64, t);
      floatx4 a0 = {0.f, 0.f, 0.f, 0.f}, a1 = a0;
      gemm2<KW2P>(tid, S1, m0, smWh, smWl, K1C, K2C, a0, a1);
      // win_t and h1_t in S1 (from G1 of this half)
      dualwait(hf, wf, t + 1);
      gemm3<KW2P>(tid, S1, m0, smWh, smWl, 0, K1C, a0, a1);
      store_gsm(tid, Gsm, a0, a1);
      __syncthreads();

      {
        int ml = tid >> 2, ppi = tid & 3;
        float v[2];
        #pragma unroll
        for (int j = 0; j < 2; ++j) {
          int nl = ppi * 8 + j * 4;
          float gi = Gsm[(nl + 0) * 65 + ml] + bia[nl + 0];
          float gf = Gsm[(nl + 1) * 65 + ml] + bia[nl + 1];
          float gg = Gsm[(nl + 2) * 65 + ml] + bia[nl + 2];
          float go = Gsm[(nl + 3) * 65 + ml] + bia[nl + 3];
          float ig = 1.f / (1.f + expf(-gi));
          float fg = 1.f / (1.f + expf(-gf));
          float gt = tanhf(gg);
          float og = 1.f / (1.f + expf(-go));
          float cn = fg * creg[j] + ig * gt;
          v[j] = og * tanhf(cn);
          creg[j] = cn;
        }
        __hip_bfloat16 h0 = bhi(v[0]), h1v = bhi(v[1]);
        unsigned int* prow = (unsigned int*)(S2 + (m0 + ml) * SLOTW);
        int dw = 288 + nt2 * 4 + ppi;      // hi dword of cols {576+nt2*8+2p, +1}
        ast(prow + dw, (unsigned int)bbits(h0) | ((unsigned int)bbits(h1v) << 16));
        if (t == T - 1) {
          int hg = nt2 * 8 + 2 * ppi;
          h2f[(m0 + ml) * H + hg]     = v[0];  c2f[(m0 + ml) * H + hg]     = creg[0];
          h2f[(m0 + ml) * H + hg + 1] = v[1];  c2f[(m0 + ml) * H + hg + 1] = creg[1];
        }
      }
      flag_store(h2g + nt2, t + 1);        // h2 slice published
    }
  }
}

// ---------------- final GEMM: out[BT x 121] = h2 @ W2^T + b2 ----------------
__global__ __launch_bounds__(256) void k_out(
    const __hip_bfloat16* __restrict__ fxHL, const __hip_bfloat16* __restrict__ w2b,
    const float* __restrict__ b2, float* __restrict__ dout)
{
  int bid = blockIdx.x, tid = threadIdx.x;
  int mblk = bid >> 1, nblk = bid & 1;
  int wv = tid >> 6, lane = tid & 63;
  int lm = lane & 15, lk = (lane >> 4) << 3;
  int m0 = mblk * 128 + wv * 32;
  int n0 = nblk * 64;
  int r0 = m0 + lm, r1 = m0 + 16 + lm;
  const __hip_bfloat16* a0p = fxHL + (size_t)((r0 & 255) + 2) * SLOTE + (r0 >> 8) * SLOTW + 576;
  const __hip_bfloat16* a1p = fxHL + (size_t)((r1 & 255) + 2) * SLOTE + (r1 >> 8) * SLOTW + 576;
  floatx4 zz = {0.f, 0.f, 0.f, 0.f};
  floatx4 acc[2][4];
  #pragma unroll
  for (int mt = 0; mt < 2; ++mt)
    #pragma unroll
    for (int nt = 0; nt < 4; ++nt) acc[mt][nt] = zz;
  #pragma unroll
  for (int c = 0; c < 16; ++c) {
    int col = c * 32 + lk;
    short8 va0 = *(const short8*)(a0p + col);
    short8 va1 = *(const short8*)(a1p + col);
    short8 vb[4];
    #pragma unroll
    for (int nt = 0; nt < 4; ++nt)
      vb[nt] = *(const short8*)(w2b + (size_t)(n0 + nt * 16 + lm) * 512 + col);
    #pragma unroll
    for (int nt = 0; nt < 4; ++nt) {
      acc[0][nt] = __builtin_amdgcn_mfma_f32_16x16x32_bf16(va0, vb[nt], acc[0][nt], 0, 0, 0);
      acc[1][nt] = __builtin_amdgcn_mfma_f32_16x16x32_bf16(va1, vb[nt], acc[1][nt], 0, 0, 0);
    }
  }
  int rr = (lane >> 4) << 2;
  #pragma unroll
  for (int mt = 0; mt < 2; ++mt)
    #pragma unroll
    for (int nt = 0; nt < 4; ++nt)
      #pragma unroll
      for (int r = 0; r < 4; ++r) {
        int m = m0 + mt * 16 + rr + r;
        int n = n0 + nt * 16 + lm;
        if (n < OUTW) dout[(size_t)m * OUTW + n] = acc[mt][nt][r] + b2[n];
      }
}

// ---------------- host ----------------
extern "C" void kernel_launch(void* const* d_in, const int* in_sizes, int n_in,
                              void* d_out, int out_size, void* d_ws, size_t ws_size,
                              hipStream_t stream)
{
  (void)in_sizes; (void)n_in; (void)out_size; (void)ws_size;
  const float* x    = (const float*)d_in[0];
  const float* sent = (const float*)d_in[1];
  const float* h1h  = (const float*)d_in[2];
  const float* h1c  = (const float*)d_in[3];
  const float* h2h  = (const float*)d_in[4];
  const float* h2c  = (const float*)d_in[5];
  const float* Wihc = (const float*)d_in[6];
  const float* Whhc = (const float*)d_in[7];
  const float* bc   = (const float*)d_in[8];
  const float* Wihl = (const float*)d_in[9];
  const float* Whhl = (const float*)d_in[10];
  const float* bl   = (const float*)d_in[11];
  const float* W1   = (const float*)d_in[12];
  const float* b1   = (const float*)d_in[13];
  const float* W2   = (const float*)d_in[14];
  const float* b2   = (const float*)d_in[15];

  float* out = (float*)d_out;
  float* h1f = out + (size_t)B * T * OUTW;
  float* c1f = h1f + (size_t)B * H;
  float* h2f = c1f + (size_t)B * H;
  float* c2f = h2f + (size_t)B * H;

  char* p = (char*)d_ws;
  auto carve = [&](size_t bytes) { char* r = p; p += (bytes + 255) & ~(size_t)255; return r; };
  __hip_bfloat16* fxHL = (__hip_bfloat16*)carve((size_t)NSLOT * SLOTE * 2);
  __hip_bfloat16* wc1  = (__hip_bfloat16*)carve((size_t)NG * K1 * 2);
  __hip_bfloat16* wc1l = (__hip_bfloat16*)carve((size_t)NG * K1 * 2);
  __hip_bfloat16* wc2  = (__hip_bfloat16*)carve((size_t)NG * K2 * 2);
  __hip_bfloat16* wc2l = (__hip_bfloat16*)carve((size_t)NG * K2 * 2);
  __hip_bfloat16* w2b  = (__hip_bfloat16*)carve((size_t)128 * 512 * 2);
  float* bi1 = (float*)carve((size_t)NG * 4);
  float* bi2 = (float*)carve((size_t)NG * 4);
  int*   ctl = (int*)carve((size_t)512 * 4);

  static bool attr_set = false;
  if (!attr_set) {
    (void)hipFuncSetAttribute((const void*)k_persist,
                              hipFuncAttributeMaxDynamicSharedMemorySize, LDS_SZ);
    attr_set = true;
  }

  k_pre<<<14226, 256, 0, stream>>>(x, h1h, h2h, Wihc, Whhc, bc, Wihl, Whhl, bl, W2,
                                   fxHL, wc1, wc1l, wc2, wc2l, w2b, bi1, bi2, ctl);
  k_persist<<<256, 256, LDS_SZ, stream>>>(fxHL, wc1, wc1l, wc2, wc2l, bi1, bi2,
                                          h1c, h2c, x, sent, W1, b1, ctl,
                                          h1f, c1f, h2f, c2f);
  k_out<<<512, 256, 0, stream>>>(fxHL, w2b, b2, out);
}

// Round 8
// 3005.163 us; speedup vs baseline: 5.4307x; 1.1076x over previous
//
#include <hip/hip_runtime.h>
#include <hip/hip_bf16.h>
#include <math.h>

typedef __attribute__((ext_vector_type(8))) short short8;
typedef __attribute__((ext_vector_type(4))) float floatx4;

#define DEVFN static __device__ __forceinline__

constexpr int B = 128, T = 256, H = 512;
constexpr int OUTW = 121;
// fxHL slot row layout (per batch row, per time slot), elems:
//   hi: [x(3) win(60) pad(1) h1(512) h2(512)] = 1088
//   lo: cols 0..575 only (x,win,h1)           = 576
constexpr int SLOTW = 1664;              // row stride in elems (hi 1088 + lo 576)
constexpr int LOOF  = 1088;              // lo region offset within row
constexpr int SLOTE = B * SLOTW;         // elems per time slot
constexpr int NSLOT = T + 2;
constexpr int NG  = 2048;                // 4*H gate rows (interleaved n' = hcol*4+gate)
constexpr int K1  = 576,  K1C = 18;
constexpr int K2  = 1088, K2C = 34;
constexpr int KW1P = 584, KW2P = 1096;   // LDS weight row pads

// ---- LDS offsets (bytes) ----
// G1 path. NOTE: hs/pp alias the Gsm region — window phase and GEMM phase are
// temporally disjoint (separated by barriers), verified in-source below.
constexpr int O_WH1 = 0;                 // 32*584*2 = 37376
constexpr int O_WL1 = 37376;             // -> 74752
constexpr int O_W1S = 74752;             // 30*520*4 = 62400 -> 137152
constexpr int O_GSM = 137152;            // 32*65*4 = 8320 -> 145472
constexpr int O_HS  = 137152;            // 528*4 = 2112 (alias in Gsm; also winv)
constexpr int O_PP  = 139264;            // 240*4 = 960 (alias in Gsm)
constexpr int O_IPL = 145472;            // 30*4
constexpr int O_KL  = 145592;            // 10*4
constexpr int O_PHL = 145632;            // 64*4
constexpr int O_WAC = 145888;            // 240*4
constexpr int O_KPR = 146848;            // 10*4
constexpr int O_B1S = 146888;            // 30*4
constexpr int O_BIA = 147008;            // 32*4 -> 147136
constexpr int O_SENT = 147136;           // 64*60 fp32 = 15360 -> 162496
// G2 path:
constexpr int O_WH2 = 0;                 // 32*1096*2 = 70144
constexpr int O_WL2 = 70144;             // -> 140288
constexpr int O_GS2 = 140288;            // 8320 -> 148608
constexpr int O_BI2 = 148608;            // 128 -> 148736
constexpr int LDS_SZ = 162496;

DEVFN __hip_bfloat16 bhi(float v) { return __float2bfloat16(v); }
DEVFN __hip_bfloat16 blo(float v, __hip_bfloat16 h) { return __float2bfloat16(v - __bfloat162float(h)); }
DEVFN float bf2f(__hip_bfloat16 h) { return __bfloat162float(h); }
DEVFN unsigned short bbits(__hip_bfloat16 h) { union { __hip_bfloat16 h; unsigned short u; } c; c.h = h; return c.u; }
DEVFN unsigned int pack2(float a, float b) {
  return (unsigned int)bbits(bhi(a)) | ((unsigned int)bbits(bhi(b)) << 16);
}
DEVFN void ast(unsigned int* p, unsigned int v) {
  __hip_atomic_store(p, v, __ATOMIC_RELAXED, __HIP_MEMORY_SCOPE_AGENT);
}
DEVFN int ald(int* p) {
  return __hip_atomic_load(p, __ATOMIC_RELAXED, __HIP_MEMORY_SCOPE_AGENT);
}

// wait until flags[i] >= target for i in [0,n) (n<=256); wave-coalesced polls
DEVFN void waitflags(int* flags, int n, int target) {
  if ((int)threadIdx.x < n) {
    int g = 0;
    while (ald(&flags[threadIdx.x]) < target && g < (1 << 22)) { ++g; __builtin_amdgcn_s_sleep(1); }
  }
  asm volatile("" ::: "memory");
  __syncthreads();
}
// wait on two 64-flag arrays
DEVFN void dualwait(int* fa, int* fb, int target) {
  int tid = threadIdx.x;
  if (tid < 128) {
    int* f = (tid < 64) ? fa + tid : fb + (tid - 64);
    int g = 0;
    while (ald(f) < target && g < (1 << 22)) { ++g; __builtin_amdgcn_s_sleep(1); }
  }
  asm volatile("" ::: "memory");
  __syncthreads();
}
// drain own stores, then publish flag value (single store, no atomic RMW)
DEVFN void flag_store(int* flag, int val) {
  asm volatile("s_waitcnt vmcnt(0)" ::: "memory");
  __syncthreads();
  if (threadIdx.x == 0)
    __hip_atomic_store(flag, val, __ATOMIC_RELAXED, __HIP_MEMORY_SCOPE_AGENT);
}

// ---------------- precompute ----------------
__global__ __launch_bounds__(256) void k_pre(
    const float* __restrict__ x, const float* __restrict__ h1h, const float* __restrict__ h2h,
    const float* __restrict__ Wihc, const float* __restrict__ Whhc, const float* __restrict__ bc,
    const float* __restrict__ Wihl, const float* __restrict__ Whhl, const float* __restrict__ bl,
    const float* __restrict__ W2,
    __hip_bfloat16* __restrict__ fxHL,
    __hip_bfloat16* __restrict__ wc1, __hip_bfloat16* __restrict__ wc1l,
    __hip_bfloat16* __restrict__ wc2, __hip_bfloat16* __restrict__ wc2l,
    __hip_bfloat16* __restrict__ w2b, float* __restrict__ bi1, float* __restrict__ bi2,
    int* __restrict__ ctl)
{
  int idx = blockIdx.x * 256 + threadIdx.x;
  const int nwc1 = NG * K1, nwc2 = NG * K2, nw2b = 128 * 512, nbi = 2 * NG;
  const int nfh = B * H, nxj = T * B, nctl = 512;
  if (idx < nwc1) {
    int n = idx / K1, col = idx - n * K1;
    int src = (n & 3) * H + (n >> 2);
    float v = (col < 63) ? Wihc[src * 63 + col]
            : (col == 63 ? 0.f : Whhc[src * 512 + (col - 64)]);
    __hip_bfloat16 h = bhi(v);
    wc1[n * K1 + col] = h; wc1l[n * K1 + col] = blo(v, h);
    return;
  }
  idx -= nwc1;
  if (idx < nwc2) {
    int n = idx / K2, col = idx - n * K2;
    int src = (n & 3) * H + (n >> 2);
    float v;
    if (col < 63)       v = Wihl[src * 575 + col];
    else if (col == 63) v = 0.f;
    else if (col < 576) v = Wihl[src * 575 + (col - 1)];
    else                v = Whhl[src * 512 + (col - 576)];
    __hip_bfloat16 h = bhi(v);
    wc2[n * K2 + col] = h; wc2l[n * K2 + col] = blo(v, h);
    return;
  }
  idx -= nwc2;
  if (idx < nw2b) {
    int n = idx >> 9, col = idx & 511;
    w2b[idx] = bhi(n < OUTW ? W2[n * 512 + col] : 0.f);
    return;
  }
  idx -= nw2b;
  if (idx < nbi) {
    int n = idx & (NG - 1);
    int src = (n & 3) * H + (n >> 2);
    if (idx < NG) bi1[n] = bc[src]; else bi2[n] = bl[src];
    return;
  }
  idx -= nbi;
  if (idx < nfh) {  // slot0 h1 init (hi+lo)
    int b = idx >> 9, j = idx & 511;
    float v = h1h[idx];
    __hip_bfloat16 h = bhi(v);
    fxHL[b * SLOTW + 64 + j] = h;
    fxHL[b * SLOTW + LOOF + 64 + j] = blo(v, h);
    return;
  }
  idx -= nfh;
  if (idx < nfh) {  // slot1 h2 init (hi only)
    int b = idx >> 9, j = idx & 511;
    fxHL[(size_t)SLOTE + b * SLOTW + 576 + j] = bhi(h2h[idx]);
    return;
  }
  idx -= nfh;
  if (idx < nxj) {  // x cols {0,1} hi + lo zeros for slot t+1
    int t = idx >> 7, b = idx & 127;
    float x0 = x[(b * T + t) * 3 + 0], x1 = x[(b * T + t) * 3 + 1];
    unsigned int* ph = (unsigned int*)(fxHL + (size_t)(t + 1) * SLOTE + b * SLOTW);
    ph[0] = pack2(x0, x1);
    unsigned int* pl = (unsigned int*)(fxHL + (size_t)(t + 1) * SLOTE + b * SLOTW + LOOF);
    pl[0] = 0u;
    return;
  }
  idx -= nxj;
  if (idx < nctl) ctl[idx] = 0;
}

// ---------------- MFMA helper (A rows from global, W in LDS) ----------------
template <int KWP>
DEVFN void gemm3(int tid, const __hip_bfloat16* __restrict__ Aslot, int m0,
                 const __hip_bfloat16* __restrict__ Wh, const __hip_bfloat16* __restrict__ Wl,
                 int cbeg, int cend, floatx4& a0, floatx4& a1)
{
  const int lane = tid & 63, wv = tid >> 6;
  const int lm = lane & 15, lk = (lane >> 4) << 3;
  const __hip_bfloat16* Ar = Aslot + (size_t)(m0 + wv * 16 + lm) * SLOTW;
  const __hip_bfloat16* W0h = Wh + lm * KWP;
  const __hip_bfloat16* W1h = Wh + (16 + lm) * KWP;
  const __hip_bfloat16* W0l = Wl + lm * KWP;
  const __hip_bfloat16* W1l = Wl + (16 + lm) * KWP;
  #pragma unroll 4
  for (int c = cbeg; c < cend; ++c) {
    int col = c * 32 + lk;
    short8 va  = *(const short8*)(Ar + col);
    short8 ua  = *(const short8*)(Ar + LOOF + col);
    short8 vb0 = *(const short8*)(W0h + col);
    short8 vb1 = *(const short8*)(W1h + col);
    short8 ub0 = *(const short8*)(W0l + col);
    short8 ub1 = *(const short8*)(W1l + col);
    a0 = __builtin_amdgcn_mfma_f32_16x16x32_bf16(va, vb0, a0, 0, 0, 0);
    a1 = __builtin_amdgcn_mfma_f32_16x16x32_bf16(va, vb1, a1, 0, 0, 0);
    a0 = __builtin_amdgcn_mfma_f32_16x16x32_bf16(va, ub0, a0, 0, 0, 0);
    a1 = __builtin_amdgcn_mfma_f32_16x16x32_bf16(va, ub1, a1, 0, 0, 0);
    a0 = __builtin_amdgcn_mfma_f32_16x16x32_bf16(ua, vb0, a0, 0, 0, 0);
    a1 = __builtin_amdgcn_mfma_f32_16x16x32_bf16(ua, vb1, a1, 0, 0, 0);
  }
}

DEVFN void store_gsm(int tid, float* Gsm, floatx4 a0, floatx4 a1) {
  const int lane = tid & 63, wv = tid >> 6;
  const int lm = lane & 15, rr = (lane >> 4) << 2;
  #pragma unroll
  for (int r = 0; r < 4; ++r) {
    Gsm[lm * 65 + wv * 16 + rr + r]        = a0[r];
    Gsm[(16 + lm) * 65 + wv * 16 + rr + r] = a1[r];
  }
}

// ---------------- persistent fused kernel ----------------
__global__ __launch_bounds__(256, 1) void k_persist(
    __hip_bfloat16* __restrict__ fxHL,
    const __hip_bfloat16* __restrict__ wc1, const __hip_bfloat16* __restrict__ wc1l,
    const __hip_bfloat16* __restrict__ wc2, const __hip_bfloat16* __restrict__ wc2l,
    const float* __restrict__ bi1, const float* __restrict__ bi2,
    const float* __restrict__ c1init, const float* __restrict__ c2init,
    const float* __restrict__ xin, const float* __restrict__ sent,
    const float* __restrict__ W1, const float* __restrict__ b1,
    int* __restrict__ ctl,
    float* __restrict__ h1f, float* __restrict__ c1f,
    float* __restrict__ h2f, float* __restrict__ c2f)
{
  extern __shared__ char sm[];
  const int gid = blockIdx.x, tid = threadIdx.x;
  const int lane = tid & 63, wv = tid >> 6;
  const int lm = lane & 15, lk = (lane >> 4) << 3;

  if (gid < 128) {
    // ========== G1: window + lstm1 ==========
    const int nt1 = gid >> 1, mh = gid & 1;
    const int n0 = nt1 * 32, m0 = mh * 64;
    const int brow = mh * 64 + nt1;
    int* wf = ctl + mh * 64;
    int* hf = ctl + 128 + mh * 64;
    __hip_bfloat16* smWh = (__hip_bfloat16*)(sm + O_WH1);
    __hip_bfloat16* smWl = (__hip_bfloat16*)(sm + O_WL1);
    float* smW1 = (float*)(sm + O_W1S);
    float* Gsm  = (float*)(sm + O_GSM);
    float* hs   = (float*)(sm + O_HS);   // aliases Gsm region (window phase only)
    float* winv = (float*)(sm + O_HS);   // reused after hs is dead
    float* pp   = (float*)(sm + O_PP);   // aliases Gsm region (window phase only)
    float* ipl  = (float*)(sm + O_IPL);
    float* kl   = (float*)(sm + O_KL);
    float* phl  = (float*)(sm + O_PHL);
    float* wac  = (float*)(sm + O_WAC);
    float* kpr  = (float*)(sm + O_KPR);
    float* b1s  = (float*)(sm + O_B1S);
    float* bia  = (float*)(sm + O_BIA);
    float* ssent = (float*)(sm + O_SENT);

    for (int i = tid; i < 32 * 72; i += 256) {
      int r = i / 72, c8 = (i - r * 72) * 8;
      *(short8*)(smWh + r * KW1P + c8) = *(const short8*)(wc1  + (size_t)(n0 + r) * K1 + c8);
      *(short8*)(smWl + r * KW1P + c8) = *(const short8*)(wc1l + (size_t)(n0 + r) * K1 + c8);
    }
    for (int i = tid; i < 30 * 512; i += 256) {
      int j = i >> 9, c = i & 511;
      smW1[j * 520 + (c >> 6) * 65 + (c & 63)] = W1[i];
    }
    for (int i = tid; i < 64 * 60; i += 256)
      ssent[i] = sent[(size_t)brow * 64 * 60 + i];   // fp32 — bf16 here fails c1f (R7)
    if (tid < 30) b1s[tid] = b1[tid];
    if (tid < 10) kpr[tid] = 0.f;
    if (tid < 32) bia[tid] = bi1[n0 + tid];
    __syncthreads();

    float creg[2];
    {
      int ml = tid >> 2, ppi = tid & 3;
      creg[0] = c1init[(m0 + ml) * H + nt1 * 8 + 2 * ppi + 0];
      creg[1] = c1init[(m0 + ml) * H + nt1 * 8 + 2 * ppi + 1];
    }

    const __hip_bfloat16* W0h = smWh + lm * KW1P;
    const __hip_bfloat16* W1h = smWh + (16 + lm) * KW1P;
    const __hip_bfloat16* W0l = smWl + lm * KW1P;
    const __hip_bfloat16* W1l = smWl + (16 + lm) * KW1P;

    for (int t = 0; t < T; ++t) {
      __hip_bfloat16* S1 = fxHL + (size_t)(t + 1) * SLOTE;
      __hip_bfloat16* S0 = fxHL + (size_t)t * SLOTE;

      waitflags(hf, 64, t);   // all same-half h1_{t-1} published

      // ---- issue window h1-row loads, x scalar, then register A-prefetch ----
      const __hip_bfloat16* wrow = S0 + (size_t)brow * SLOTW;
      __hip_bfloat16 a0h = wrow[64 + tid];
      __hip_bfloat16 a0l = wrow[LOOF + 64 + tid];
      __hip_bfloat16 a1h = wrow[64 + 256 + tid];
      __hip_bfloat16 a1l = wrow[LOOF + 64 + 256 + tid];
      float x2v = xin[(brow * T + t) * 3 + 2];
      const __hip_bfloat16* Ar = S0 + (size_t)(m0 + wv * 16 + lm) * SLOTW;
      short8 pva[16], pua[16];
      #pragma unroll
      for (int c = 0; c < 16; ++c) {
        pva[c] = *(const short8*)(Ar + (c + 2) * 32 + lk);
        pua[c] = *(const short8*)(Ar + LOOF + (c + 2) * 32 + lk);
      }
      hs[(tid >> 6) * 66 + (tid & 63)] = bf2f(a0h) + bf2f(a0l);
      hs[((tid + 256) >> 6) * 66 + (tid & 63)] = bf2f(a1h) + bf2f(a1l);
      __syncthreads();

      // ---- window compute (LDS only; overlaps A-prefetch in flight) ----
      if (tid < 240) {
        int j = tid >> 3, p = tid & 7;
        const float* wp = smW1 + j * 520 + p * 65;
        const float* hv = hs + p * 66;
        float s = 0.f;
        #pragma unroll 8
        for (int k = 0; k < 64; ++k) s += hv[k] * wp[k];
        pp[tid] = s;
      }
      __syncthreads();
      if (tid < 30) {
        float s = b1s[tid];
        #pragma unroll
        for (int p = 0; p < 8; ++p) s += pp[tid * 8 + p];
        ipl[tid] = expf(s);
      }
      __syncthreads();
      if (tid < 10) {
        float kap = ipl[20 + tid] - kpr[tid];
        kpr[tid] = kap; kl[tid] = kap;
      }
      __syncthreads();
      if (tid < 64) {
        float u = (float)(tid + 1);
        float acc = 0.f;
        #pragma unroll
        for (int k = 0; k < 10; ++k) {
          float d = kl[k] - u;
          acc += ipl[k] * expf(-ipl[10 + k] * d * d);
        }
        phl[tid] = acc;
      }
      __syncthreads();
      if (tid < 240) {
        int c = tid >> 2, p = tid & 3;
        float acc = 0.f;
        #pragma unroll
        for (int s0 = 0; s0 < 16; ++s0)
          acc += phl[p * 16 + s0] * ssent[(p * 16 + s0) * 60 + c];
        wac[tid] = acc;
      }
      __syncthreads();
      if (tid < 60)
        winv[tid] = wac[tid * 4] + wac[tid * 4 + 1] + wac[tid * 4 + 2] + wac[tid * 4 + 3];
      __syncthreads();
      if (tid < 31) {  // publish win (dwords 1..31 of hi and lo line-0 region)
        int d = 1 + tid;
        int c0 = 2 * d, c1 = 2 * d + 1;
        float v0 = (c0 == 2) ? x2v : winv[c0 - 3];
        float v1 = (c1 == 63) ? 0.f : winv[c1 - 3];
        __hip_bfloat16 h0 = bhi(v0), h1v = bhi(v1);
        unsigned int* prow = (unsigned int*)(S1 + (size_t)brow * SLOTW);
        ast(prow + d, (unsigned int)bbits(h0) | ((unsigned int)bbits(h1v) << 16));
        ast(prow + (LOOF >> 1) + d,
            (unsigned int)bbits(blo(v0, h0)) | ((unsigned int)bbits(blo(v1, h1v)) << 16));
      }
      flag_store(wf + nt1, t + 1);          // win(brow) published

      // ---- h1-part MFMA from prefetched registers (no global loads) ----
      floatx4 a0 = {0.f, 0.f, 0.f, 0.f}, a1 = a0;
      #pragma unroll
      for (int c = 0; c < 16; ++c) {
        int col = (c + 2) * 32 + lk;
        short8 vb0 = *(const short8*)(W0h + col);
        short8 vb1 = *(const short8*)(W1h + col);
        short8 ub0 = *(const short8*)(W0l + col);
        short8 ub1 = *(const short8*)(W1l + col);
        a0 = __builtin_amdgcn_mfma_f32_16x16x32_bf16(pva[c], vb0, a0, 0, 0, 0);
        a1 = __builtin_amdgcn_mfma_f32_16x16x32_bf16(pva[c], vb1, a1, 0, 0, 0);
        a0 = __builtin_amdgcn_mfma_f32_16x16x32_bf16(pva[c], ub0, a0, 0, 0, 0);
        a1 = __builtin_amdgcn_mfma_f32_16x16x32_bf16(pva[c], ub1, a1, 0, 0, 0);
        a0 = __builtin_amdgcn_mfma_f32_16x16x32_bf16(pua[c], vb0, a0, 0, 0, 0);
        a1 = __builtin_amdgcn_mfma_f32_16x16x32_bf16(pua[c], vb1, a1, 0, 0, 0);
      }
      waitflags(wf, 64, t + 1);             // all wins of this half available
      gemm3<KW1P>(tid, S1, m0, smWh, smWl, 0, 2, a0, a1);
      store_gsm(tid, Gsm, a0, a1);
      __syncthreads();

      // ---- epilogue: each thread 2 adjacent h-cols of one m-row ----
      {
        int ml = tid >> 2, ppi = tid & 3;
        float v[2];
        #pragma unroll
        for (int j = 0; j < 2; ++j) {
          int nl = ppi * 8 + j * 4;
          float gi = Gsm[(nl + 0) * 65 + ml] + bia[nl + 0];
          float gf = Gsm[(nl + 1) * 65 + ml] + bia[nl + 1];
          float gg = Gsm[(nl + 2) * 65 + ml] + bia[nl + 2];
          float go = Gsm[(nl + 3) * 65 + ml] + bia[nl + 3];
          float ig = 1.f / (1.f + expf(-gi));
          float fg = 1.f / (1.f + expf(-gf));
          float gt = tanhf(gg);
          float og = 1.f / (1.f + expf(-go));
          float cn = fg * creg[j] + ig * gt;
          v[j] = og * tanhf(cn);
          creg[j] = cn;
        }
        __hip_bfloat16 h0 = bhi(v[0]), h1v = bhi(v[1]);
        unsigned int* prow = (unsigned int*)(S1 + (size_t)(m0 + ml) * SLOTW);
        int dw = 32 + nt1 * 4 + ppi;       // hi dword of cols {64+nt1*8+2p, +1}
        ast(prow + dw, (unsigned int)bbits(h0) | ((unsigned int)bbits(h1v) << 16));
        ast(prow + (LOOF >> 1) + dw,
            (unsigned int)bbits(blo(v[0], h0)) | ((unsigned int)bbits(blo(v[1], h1v)) << 16));
        if (t == T - 1) {
          int hg = nt1 * 8 + 2 * ppi;
          h1f[(m0 + ml) * H + hg]     = v[0];  c1f[(m0 + ml) * H + hg]     = creg[0];
          h1f[(m0 + ml) * H + hg + 1] = v[1];  c1f[(m0 + ml) * H + hg + 1] = creg[1];
        }
      }
      flag_store(hf + nt1, t + 1);          // h1 slice published
    }
  } else {
    // ========== G2: lstm2 ==========
    const int g = gid - 128;
    const int nt2 = g >> 1, mh = g & 1;
    const int n0 = nt2 * 32, m0 = mh * 64;
    int* wf  = ctl + mh * 64;
    int* hf  = ctl + 128 + mh * 64;
    int* h2g = ctl + 256 + mh * 64;
    __hip_bfloat16* smWh = (__hip_bfloat16*)(sm + O_WH2);
    __hip_bfloat16* smWl = (__hip_bfloat16*)(sm + O_WL2);
    float* Gsm = (float*)(sm + O_GS2);
    float* bia = (float*)(sm + O_BI2);

    for (int i = tid; i < 32 * 136; i += 256) {
      int r = i / 136, c8 = (i - r * 136) * 8;
      *(short8*)(smWh + r * KW2P + c8) = *(const short8*)(wc2  + (size_t)(n0 + r) * K2 + c8);
      *(short8*)(smWl + r * KW2P + c8) = *(const short8*)(wc2l + (size_t)(n0 + r) * K2 + c8);
    }
    if (tid < 32) bia[tid] = bi2[n0 + tid];
    __syncthreads();

    float creg[2];
    {
      int ml = tid >> 2, ppi = tid & 3;
      creg[0] = c2init[(m0 + ml) * H + nt2 * 8 + 2 * ppi + 0];
      creg[1] = c2init[(m0 + ml) * H + nt2 * 8 + 2 * ppi + 1];
    }

    const __hip_bfloat16* W0h = smWh + lm * KW2P;
    const __hip_bfloat16* W1h = smWh + (16 + lm) * KW2P;
    const __hip_bfloat16* W0l = smWl + lm * KW2P;
    const __hip_bfloat16* W1l = smWl + (16 + lm) * KW2P;

    for (int t = 0; t < T; ++t) {
      __hip_bfloat16* S1 = fxHL + (size_t)(t + 1) * SLOTE;
      __hip_bfloat16* S2 = fxHL + (size_t)(t + 2) * SLOTE;
      const __hip_bfloat16* Ar = S1 + (size_t)(m0 + wv * 16 + lm) * SLOTW;

      // own-half h2_{t-1} complete in S1 -> prefetch h2-part A (hi only)
      waitflags(h2g, 64, t);
      short8 pv2[16];
      #pragma unroll
      for (int c = 0; c < 16; ++c)
        pv2[c] = *(const short8*)(Ar + (K1C + c) * 32 + lk);
      floatx4 a0 = {0.f, 0.f, 0.f, 0.f}, a1 = a0;
      #pragma unroll
      for (int c = 0; c < 16; ++c) {
        int col = (K1C + c) * 32 + lk;
        short8 vb0 = *(const short8*)(W0h + col);
        short8 vb1 = *(const short8*)(W1h + col);
        short8 ub0 = *(const short8*)(W0l + col);
        short8 ub1 = *(const short8*)(W1l + col);
        a0 = __builtin_amdgcn_mfma_f32_16x16x32_bf16(pv2[c], vb0, a0, 0, 0, 0);
        a1 = __builtin_amdgcn_mfma_f32_16x16x32_bf16(pv2[c], vb1, a1, 0, 0, 0);
        a0 = __builtin_amdgcn_mfma_f32_16x16x32_bf16(pv2[c], ub0, a0, 0, 0, 0);
        a1 = __builtin_amdgcn_mfma_f32_16x16x32_bf16(pv2[c], ub1, a1, 0, 0, 0);
      }
      // win_t and h1_t in S1 (from G1 of this half)
      dualwait(hf, wf, t + 1);
      short8 qv[18], qu[18];
      #pragma unroll
      for (int c = 0; c < 18; ++c) {
        qv[c] = *(const short8*)(Ar + c * 32 + lk);
        qu[c] = *(const short8*)(Ar + LOOF + c * 32 + lk);
      }
      #pragma unroll
      for (int c = 0; c < 18; ++c) {
        int col = c * 32 + lk;
        short8 vb0 = *(const short8*)(W0h + col);
        short8 vb1 = *(const short8*)(W1h + col);
        short8 ub0 = *(const short8*)(W0l + col);
        short8 ub1 = *(const short8*)(W1l + col);
        a0 = __builtin_amdgcn_mfma_f32_16x16x32_bf16(qv[c], vb0, a0, 0, 0, 0);
        a1 = __builtin_amdgcn_mfma_f32_16x16x32_bf16(qv[c], vb1, a1, 0, 0, 0);
        a0 = __builtin_amdgcn_mfma_f32_16x16x32_bf16(qv[c], ub0, a0, 0, 0, 0);
        a1 = __builtin_amdgcn_mfma_f32_16x16x32_bf16(qv[c], ub1, a1, 0, 0, 0);
        a0 = __builtin_amdgcn_mfma_f32_16x16x32_bf16(qu[c], vb0, a0, 0, 0, 0);
        a1 = __builtin_amdgcn_mfma_f32_16x16x32_bf16(qu[c], vb1, a1, 0, 0, 0);
      }
      store_gsm(tid, Gsm, a0, a1);
      __syncthreads();

      {
        int ml = tid >> 2, ppi = tid & 3;
        float v[2];
        #pragma unroll
        for (int j = 0; j < 2; ++j) {
          int nl = ppi * 8 + j * 4;
          float gi = Gsm[(nl + 0) * 65 + ml] + bia[nl + 0];
          float gf = Gsm[(nl + 1) * 65 + ml] + bia[nl + 1];
          float gg = Gsm[(nl + 2) * 65 + ml] + bia[nl + 2];
          float go = Gsm[(nl + 3) * 65 + ml] + bia[nl + 3];
          float ig = 1.f / (1.f + expf(-gi));
          float fg = 1.f / (1.f + expf(-gf));
          float gt = tanhf(gg);
          float og = 1.f / (1.f + expf(-go));
          float cn = fg * creg[j] + ig * gt;
          v[j] = og * tanhf(cn);
          creg[j] = cn;
        }
        __hip_bfloat16 h0 = bhi(v[0]), h1v = bhi(v[1]);
        unsigned int* prow = (unsigned int*)(S2 + (size_t)(m0 + ml) * SLOTW);
        int dw = 288 + nt2 * 4 + ppi;      // hi dword of cols {576+nt2*8+2p, +1}
        ast(prow + dw, (unsigned int)bbits(h0) | ((unsigned int)bbits(h1v) << 16));
        if (t == T - 1) {
          int hg = nt2 * 8 + 2 * ppi;
          h2f[(m0 + ml) * H + hg]     = v[0];  c2f[(m0 + ml) * H + hg]     = creg[0];
          h2f[(m0 + ml) * H + hg + 1] = v[1];  c2f[(m0 + ml) * H + hg + 1] = creg[1];
        }
      }
      flag_store(h2g + nt2, t + 1);        // h2 slice published
    }
  }
}

// ---------------- final GEMM: out[BT x 121] = h2 @ W2^T + b2 ----------------
__global__ __launch_bounds__(256) void k_out(
    const __hip_bfloat16* __restrict__ fxHL, const __hip_bfloat16* __restrict__ w2b,
    const float* __restrict__ b2, float* __restrict__ dout)
{
  int bid = blockIdx.x, tid = threadIdx.x;
  int mblk = bid >> 1, nblk = bid & 1;
  int wv = tid >> 6, lane = tid & 63;
  int lm = lane & 15, lk = (lane >> 4) << 3;
  int m0 = mblk * 128 + wv * 32;
  int n0 = nblk * 64;
  int r0 = m0 + lm, r1 = m0 + 16 + lm;
  const __hip_bfloat16* a0p = fxHL + (size_t)((r0 & 255) + 2) * SLOTE + (r0 >> 8) * SLOTW + 576;
  const __hip_bfloat16* a1p = fxHL + (size_t)((r1 & 255) + 2) * SLOTE + (r1 >> 8) * SLOTW + 576;
  floatx4 zz = {0.f, 0.f, 0.f, 0.f};
  floatx4 acc[2][4];
  #pragma unroll
  for (int mt = 0; mt < 2; ++mt)
    #pragma unroll
    for (int nt = 0; nt < 4; ++nt) acc[mt][nt] = zz;
  #pragma unroll
  for (int c = 0; c < 16; ++c) {
    int col = c * 32 + lk;
    short8 va0 = *(const short8*)(a0p + col);
    short8 va1 = *(const short8*)(a1p + col);
    short8 vb[4];
    #pragma unroll
    for (int nt = 0; nt < 4; ++nt)
      vb[nt] = *(const short8*)(w2b + (size_t)(n0 + nt * 16 + lm) * 512 + col);
    #pragma unroll
    for (int nt = 0; nt < 4; ++nt) {
      acc[0][nt] = __builtin_amdgcn_mfma_f32_16x16x32_bf16(va0, vb[nt], acc[0][nt], 0, 0, 0);
      acc[1][nt] = __builtin_amdgcn_mfma_f32_16x16x32_bf16(va1, vb[nt], acc[1][nt], 0, 0, 0);
    }
  }
  int rr = (lane >> 4) << 2;
  #pragma unroll
  for (int mt = 0; mt < 2; ++mt)
    #pragma unroll
    for (int nt = 0; nt < 4; ++nt)
      #pragma unroll
      for (int r = 0; r < 4; ++r) {
        int m = m0 + mt * 16 + rr + r;
        int n = n0 + nt * 16 + lm;
        if (n < OUTW) dout[(size_t)m * OUTW + n] = acc[mt][nt][r] + b2[n];
      }
}

// ---------------- host ----------------
extern "C" void kernel_launch(void* const* d_in, const int* in_sizes, int n_in,
                              void* d_out, int out_size, void* d_ws, size_t ws_size,
                              hipStream_t stream)
{
  (void)in_sizes; (void)n_in; (void)out_size; (void)ws_size;
  const float* x    = (const float*)d_in[0];
  const float* sent = (const float*)d_in[1];
  const float* h1h  = (const float*)d_in[2];
  const float* h1c  = (const float*)d_in[3];
  const float* h2h  = (const float*)d_in[4];
  const float* h2c  = (const float*)d_in[5];
  const float* Wihc = (const float*)d_in[6];
  const float* Whhc = (const float*)d_in[7];
  const float* bc   = (const float*)d_in[8];
  const float* Wihl = (const float*)d_in[9];
  const float* Whhl = (const float*)d_in[10];
  const float* bl   = (const float*)d_in[11];
  const float* W1   = (const float*)d_in[12];
  const float* b1   = (const float*)d_in[13];
  const float* W2   = (const float*)d_in[14];
  const float* b2   = (const float*)d_in[15];

  float* out = (float*)d_out;
  float* h1f = out + (size_t)B * T * OUTW;
  float* c1f = h1f + (size_t)B * H;
  float* h2f = c1f + (size_t)B * H;
  float* c2f = h2f + (size_t)B * H;

  char* p = (char*)d_ws;
  auto carve = [&](size_t bytes) { char* r = p; p += (bytes + 255) & ~(size_t)255; return r; };
  __hip_bfloat16* fxHL = (__hip_bfloat16*)carve((size_t)NSLOT * SLOTE * 2);
  __hip_bfloat16* wc1  = (__hip_bfloat16*)carve((size_t)NG * K1 * 2);
  __hip_bfloat16* wc1l = (__hip_bfloat16*)carve((size_t)NG * K1 * 2);
  __hip_bfloat16* wc2  = (__hip_bfloat16*)carve((size_t)NG * K2 * 2);
  __hip_bfloat16* wc2l = (__hip_bfloat16*)carve((size_t)NG * K2 * 2);
  __hip_bfloat16* w2b  = (__hip_bfloat16*)carve((size_t)128 * 512 * 2);
  float* bi1 = (float*)carve((size_t)NG * 4);
  float* bi2 = (float*)carve((size_t)NG * 4);
  int*   ctl = (int*)carve((size_t)512 * 4);

  static bool attr_set = false;
  if (!attr_set) {
    (void)hipFuncSetAttribute((const void*)k_persist,
                              hipFuncAttributeMaxDynamicSharedMemorySize, LDS_SZ);
    attr_set = true;
  }

  k_pre<<<14226, 256, 0, stream>>>(x, h1h, h2h, Wihc, Whhc, bc, Wihl, Whhl, bl, W2,
                                   fxHL, wc1, wc1l, wc2, wc2l, w2b, bi1, bi2, ctl);
  k_persist<<<256, 256, LDS_SZ, stream>>>(fxHL, wc1, wc1l, wc2, wc2l, bi1, bi2,
                                          h1c, h2c, x, sent, W1, b1, ctl,
                                          h1f, c1f, h2f, c2f);
  k_out<<<512, 256, 0, stream>>>(fxHL, w2b, b2, out);
}